// Round 3
// baseline (681.383 us; speedup 1.0000x reference)
//
#include <hip/hip_runtime.h>

// NPG model: E=4, B=16384, STATE=29, ACT=8, HID=512.
// R3: transposed MFMA (D = W^T X^T) so packed weights are the A-operand and
// C/D emerges feature-major -> packed b64 LDS writes (R2's 2.3e7 conflict
// cycles were scalar ds_write_b16 of h1/h2). Leg layer2 (o<4) done in VALU
// from layer1 regs (no h2 materialization, fp32-exact) + shfl quad-reduce +
// LDS partial. Pose layer2 stays MFMA via 64-row h2c. ~76 barriers/block.

#define E_ 4
#define B_ 16384
#define H1S 520   // bf16 elems; 1040B row = 16B-aligned, 4-bank skew (reads 2-way free)
#define H2S 136
#define A0S 40

typedef float f32x4 __attribute__((ext_vector_type(4)));
typedef __bf16 bf16x8 __attribute__((ext_vector_type(8)));
typedef __bf16 bf16x4 __attribute__((ext_vector_type(4)));

__device__ __forceinline__ f32x4 mfma16(bf16x8 a, bf16x8 b, f32x4 c) {
  return __builtin_amdgcn_mfma_f32_16x16x32_bf16(a, b, c, 0, 0, 0);
}

__device__ __forceinline__ void fmt_map(int k, int& ib, int& j) {
  if (k < 8) { ib = k >> 1; j = (k & 1) ? 2 : 0; }
  else { int k8 = k - 8; ib = k8 >> 1; j = (k8 & 1) ? 3 : 1; }
}

// packed fragment index for W(KxN): lane holds W[kt*32+quad*8+j][nt*16+l16]
__device__ __forceinline__ int pidx(int KT, int k, int n) {
  return (((n >> 4) * KT + (k >> 5)) * 64 + ((k >> 3) & 3) * 16 + (n & 15)) * 8 + (k & 7);
}

// ---------------- prep: coalesced-read pack to bf16 fragments ---------------
__global__ void prep_kernel(const float* __restrict__ wl0, const float* __restrict__ wl1,
                            const float* __restrict__ wp0, const float* __restrict__ wp1,
                            const float* __restrict__ wp2,
                            const float* __restrict__ bl0, const float* __restrict__ bp0,
                            const float* __restrict__ mu_leg, const float* __restrict__ sigma_leg,
                            const float* __restrict__ mu_pose, const float* __restrict__ sigma_pose,
                            __bf16* __restrict__ WL0p, __bf16* __restrict__ WL1p,
                            __bf16* __restrict__ WP0p, __bf16* __restrict__ WP1p,
                            __bf16* __restrict__ WP2p,
                            float* __restrict__ bl0f, float* __restrict__ bp0f)
{
  // ranges: W0l real 12288 | W0l pad 53248 | W1l 1048576 | W0p real 59392 |
  //         W0p pad 6144 | W1p 1048576 | W2p 32768 | bias 4096
  const int total = 12288 + 53248 + 1048576 + 59392 + 6144 + 1048576 + 32768 + 4096;
  for (int idx0 = blockIdx.x * blockDim.x + threadIdx.x; idx0 < total;
       idx0 += gridDim.x * blockDim.x) {
    int x = idx0;
    if (x < 12288) {
      int e = x / 3072, r = x - e * 3072, k = r >> 9, n = r & 511;
      WL0p[e * 16384 + pidx(1, k, n)] =
          (__bf16)(wl0[(e * 6 + k) * 512 + n] / (sigma_leg[k] + 1e-8f));
    } else if ((x -= 12288) < 53248) {
      int e = x / 13312, r = x - e * 13312, k = 6 + (r >> 9), n = r & 511;
      WL0p[e * 16384 + pidx(1, k, n)] = (__bf16)0.f;
    } else if ((x -= 53248) < 1048576) {
      int e = x >> 18, r = x & 262143, k = r >> 9, n = r & 511;
      WL1p[(size_t)e * 262144 + pidx(16, k, n)] = (__bf16)wl1[((size_t)(e * 512 + k)) * 512 + n];
    } else if ((x -= 1048576) < 59392) {
      int e = x / 14848, r = x - e * 14848, k = r >> 9, n = r & 511;
      WP0p[e * 16384 + pidx(1, k, n)] =
          (__bf16)(wp0[(e * 29 + k) * 512 + n] / (sigma_pose[k] + 1e-8f));
    } else if ((x -= 59392) < 6144) {
      int e = x / 1536, r = x - e * 1536, k = 29 + (r >> 9), n = r & 511;
      WP0p[e * 16384 + pidx(1, k, n)] = (__bf16)0.f;
    } else if ((x -= 6144) < 1048576) {
      int e = x >> 18, r = x & 262143, k = r >> 9, n = r & 511;
      WP1p[(size_t)e * 262144 + pidx(16, k, n)] = (__bf16)wp1[((size_t)(e * 512 + k)) * 512 + n];
    } else if ((x -= 1048576) < 32768) {
      int e = x >> 13, r = x & 8191, k = r >> 4, n = r & 15;
      WP2p[e * 8192 + pidx(16, k, n)] = (__bf16)wp2[(e * 512 + k) * 26 + n];
    } else {
      x -= 32768;  // bias folds: b0' = b0 - sum_k mu[k]/(sigma[k]+eps) * W0[k,:]
      if (x < 2048) {
        int e = x >> 9, n = x & 511;
        float s = bl0[e * 512 + n];
        #pragma unroll
        for (int k = 0; k < 6; ++k)
          s -= mu_leg[k] / (sigma_leg[k] + 1e-8f) * wl0[(e * 6 + k) * 512 + n];
        bl0f[e * 512 + n] = s;
      } else {
        x -= 2048;
        int e = x >> 9, n = x & 511;
        float s = bp0[e * 512 + n];
        for (int k = 0; k < 29; ++k)
          s -= mu_pose[k] / (sigma_pose[k] + 1e-8f) * wp0[(e * 29 + k) * 512 + n];
        bp0f[e * 512 + n] = s;
      }
    }
  }
}

// ---------------- fused model kernel ----------------------------------------
__global__ __launch_bounds__(512) void fused_kernel(
    const float* __restrict__ state, const float* __restrict__ act,
    const float* __restrict__ bl1, const float* __restrict__ bl2,
    const float* __restrict__ bp1, const float* __restrict__ bp2,
    const float* __restrict__ wl2,  // fp32, used directly by VALU layer2
    const float* __restrict__ mu_t_leg, const float* __restrict__ sigma_t_leg,
    const float* __restrict__ mu_t_pose, const float* __restrict__ sigma_t_pose,
    const __bf16* __restrict__ WL0p, const __bf16* __restrict__ WL1p,
    const __bf16* __restrict__ WP0p, const __bf16* __restrict__ WP1p,
    const __bf16* __restrict__ WP2p,
    const float* __restrict__ bl0f, const float* __restrict__ bp0f,
    float* __restrict__ out)
{
  __shared__ alignas(16) __bf16 h1[128 * H1S];   // 133120 B
  __shared__ alignas(16) __bf16 h2c[64 * H2S];   // 17408 B (union: a0 staging)
  __shared__ float ldiff[64][16];                // 4096 B
  __shared__ float legpart[128 * 16];            // 8192 B  [L][ng][o]
  __bf16* a0s = h2c;                             // leg a0 128x40=10240B fits

  const int tid = threadIdx.x;
  const int wv = tid >> 6;
  const int lane = tid & 63;
  const int quad = lane >> 4;
  const int l16 = lane & 15;
  const int b0 = blockIdx.x * 64;

  f32x4 posacc = {0.f, 0.f, 0.f, 0.f};
  float legreg[2] = {0.f, 0.f};

  for (int e = 0; e < E_; ++e) {
    const float* se = state + (size_t)e * B_ * 29;
    const float* ae = act + (size_t)e * B_ * 8;

    // ================= leg MLP: 2 passes of 128 leg rows =================
    {
      const __bf16* W0 = WL0p + e * 16384;
      const __bf16* W1 = WL1p + (size_t)e * 262144;
      const float* b0v = bl0f + e * 512;
      const float* b1v = bl1 + e * 512;
      const float* w2l = wl2 + (size_t)e * 4096;  // 512x8 fp32

      for (int half = 0; half < 2; ++half) {
        __syncthreads();   // (A) a0s / legpart regions free
        for (int i = tid; i < 128 * 32; i += 512) {
          int r = i >> 5, c = i & 31;
          float v = 0.f;
          if (c < 6) {
            int ib = r >> 5;
            int b = b0 + half * 32 + (r & 31);
            const float* sp = se + (size_t)b * 29;
            if (c == 0) v = sp[13 + 2 * ib];
            else if (c == 1) v = sp[21 + 2 * ib];
            else if (c == 2) v = sp[14 + 2 * ib];
            else if (c == 3) v = sp[22 + 2 * ib];
            else if (c == 4) v = ae[(size_t)b * 8 + 2 * ib];
            else v = ae[(size_t)b * 8 + 2 * ib + 1];
          }
          a0s[r * A0S + c] = (__bf16)v;
        }
        __syncthreads();   // (B) a0 ready

        // ---- layer0 (transposed): h1[batch][n], packed b64 writes
        {
          bf16x8 wfr[4]; f32x4 bias[4];
          #pragma unroll
          for (int i = 0; i < 4; ++i) {
            int nt = wv * 4 + i;
            wfr[i] = *(const bf16x8*)(W0 + (nt * 64 + lane) * 8);
            bias[i] = *(const f32x4*)(b0v + nt * 16 + quad * 4);
          }
          for (int bt = 0; bt < 8; ++bt) {
            bf16x8 xfr = *(const bf16x8*)&a0s[(bt * 16 + l16) * A0S + quad * 8];
            #pragma unroll
            for (int i = 0; i < 4; ++i) {
              f32x4 acc = mfma16(wfr[i], xfr, bias[i]);
              bf16x4 p;
              #pragma unroll
              for (int r = 0; r < 4; ++r) p[r] = (__bf16)fmaxf(acc[r], 0.f);
              *(bf16x4*)&h1[(bt * 16 + l16) * H1S + (wv * 4 + i) * 16 + quad * 4] = p;
            }
          }
        }
        __syncthreads();   // (C) h1 ready

        // ---- layer1 (transposed) + VALU layer2 (o<4) from regs
        const int ng = wv >> 1;   // 2 n-tiles each
        const int bg = wv & 1;    // 4 batch-tiles each
        f32x4 po[4] = {{0,0,0,0},{0,0,0,0},{0,0,0,0},{0,0,0,0}};
        for (int cc = 0; cc < 4; ++cc) {
          f32x4 acc[4][2];
          #pragma unroll
          for (int ct = 0; ct < 2; ++ct) {
            f32x4 bias = *(const f32x4*)(b1v + cc * 128 + (ng * 2 + ct) * 16 + quad * 4);
            #pragma unroll
            for (int bb = 0; bb < 4; ++bb) acc[bb][ct] = bias;
          }
          const int ntb = cc * 8 + ng * 2;
          #pragma unroll 4
          for (int kt = 0; kt < 16; ++kt) {
            bf16x8 wf0 = *(const bf16x8*)(W1 + ((size_t)((ntb + 0) * 16 + kt) * 64 + lane) * 8);
            bf16x8 wf1 = *(const bf16x8*)(W1 + ((size_t)((ntb + 1) * 16 + kt) * 64 + lane) * 8);
            bf16x8 hf[4];
            #pragma unroll
            for (int bb = 0; bb < 4; ++bb)
              hf[bb] = *(const bf16x8*)&h1[((bg * 4 + bb) * 16 + l16) * H1S + kt * 32 + quad * 8];
            #pragma unroll
            for (int bb = 0; bb < 4; ++bb) {
              acc[bb][0] = mfma16(wf0, hf[bb], acc[bb][0]);
              acc[bb][1] = mfma16(wf1, hf[bb], acc[bb][1]);
            }
          }
          // layer2 partials: po[bb][o] += relu(h2) * W2[n][o], o=0..3
          #pragma unroll
          for (int ct = 0; ct < 2; ++ct) {
            #pragma unroll
            for (int r = 0; r < 4; ++r) {
              int n = (ntb + ct) * 16 + quad * 4 + r;
              f32x4 w2v = *(const f32x4*)(w2l + n * 8);
              #pragma unroll
              for (int bb = 0; bb < 4; ++bb) {
                float h = fmaxf(acc[bb][ct][r], 0.f);
                po[bb] += h * w2v;
              }
            }
          }
        }
        // quad-reduce (n-dim lives on quads; batch l16 preserved)
        #pragma unroll
        for (int bb = 0; bb < 4; ++bb) {
          #pragma unroll
          for (int c = 0; c < 4; ++c) {
            po[bb][c] += __shfl_xor(po[bb][c], 16);
            po[bb][c] += __shfl_xor(po[bb][c], 32);
          }
        }
        if (quad == 0) {
          #pragma unroll
          for (int bb = 0; bb < 4; ++bb)
            *(f32x4*)&legpart[((bg * 4 + bb) * 16 + l16) * 16 + ng * 4] = po[bb];
        }
        __syncthreads();   // (D) legpart ready
        {
          int L = tid >> 2, o = tid & 3;
          float s = legpart[L * 16 + o] + legpart[L * 16 + 4 + o] +
                    legpart[L * 16 + 8 + o] + legpart[L * 16 + 12 + o] + bl2[e * 8 + o];
          s = s * (sigma_t_leg[o] + 1e-8f) + mu_t_leg[o];
          ldiff[half * 32 + (L & 31)][(L >> 5) * 4 + o] = s;
        }
      } // half
    }
    __syncthreads();       // (E) ldiff ready

    // ================= pose MLP: 64 rows =================
    for (int i = tid; i < 64 * 32; i += 512) {
      int t = i >> 5, c = i & 31;
      float v = 0.f;
      if (c < 13) v = se[(size_t)(b0 + t) * 29 + c];
      else if (c < 29) { int ib, j; fmt_map(c - 13, ib, j); v = ldiff[t][ib * 4 + j]; }
      a0s[t * A0S + c] = (__bf16)v;
    }
    {  // legs output accumulation (registers)
      #pragma unroll
      for (int jj = 0; jj < 2; ++jj) {
        int idx = tid * 2 + jj, t = idx >> 4, k = idx & 15;
        int ib, j; fmt_map(k, ib, j);
        legreg[jj] += se[(size_t)(b0 + t) * 29 + 13 + k] + ldiff[t][ib * 4 + j];
      }
    }
    __syncthreads();       // (F) a0p ready

    // ---- pose layer0
    {
      const __bf16* W0 = WP0p + e * 16384;
      const float* b0v = bp0f + e * 512;
      bf16x8 wfr[4]; f32x4 bias[4];
      #pragma unroll
      for (int i = 0; i < 4; ++i) {
        int nt = wv * 4 + i;
        wfr[i] = *(const bf16x8*)(W0 + (nt * 64 + lane) * 8);
        bias[i] = *(const f32x4*)(b0v + nt * 16 + quad * 4);
      }
      for (int bt = 0; bt < 4; ++bt) {
        bf16x8 xfr = *(const bf16x8*)&a0s[(bt * 16 + l16) * A0S + quad * 8];
        #pragma unroll
        for (int i = 0; i < 4; ++i) {
          f32x4 acc = mfma16(wfr[i], xfr, bias[i]);
          bf16x4 p;
          #pragma unroll
          for (int r = 0; r < 4; ++r) p[r] = (__bf16)fmaxf(acc[r], 0.f);
          *(bf16x4*)&h1[(bt * 16 + l16) * H1S + (wv * 4 + i) * 16 + quad * 4] = p;
        }
      }
    }
    __syncthreads();       // (G) h1 ready (a0p reads done)

    // ---- pose layer1 + MFMA layer2 via h2c
    {
      const __bf16* W1 = WP1p + (size_t)e * 262144;
      const __bf16* W2 = WP2p + e * 8192;
      const float* b1v = bp1 + e * 512;
      const int ng = wv >> 1;   // 2 n-tiles
      const int bg = wv & 1;    // 2 batch-tiles
      f32x4 po;
      #pragma unroll
      for (int r = 0; r < 4; ++r) po[r] = bp2[e * 26 + quad * 4 + r];

      for (int cc = 0; cc < 4; ++cc) {
        f32x4 acc[2][2];
        #pragma unroll
        for (int ct = 0; ct < 2; ++ct) {
          f32x4 bias = *(const f32x4*)(b1v + cc * 128 + (ng * 2 + ct) * 16 + quad * 4);
          #pragma unroll
          for (int bb = 0; bb < 2; ++bb) acc[bb][ct] = bias;
        }
        const int ntb = cc * 8 + ng * 2;
        #pragma unroll 4
        for (int kt = 0; kt < 16; ++kt) {
          bf16x8 wf0 = *(const bf16x8*)(W1 + ((size_t)((ntb + 0) * 16 + kt) * 64 + lane) * 8);
          bf16x8 wf1 = *(const bf16x8*)(W1 + ((size_t)((ntb + 1) * 16 + kt) * 64 + lane) * 8);
          bf16x8 hf[2];
          #pragma unroll
          for (int bb = 0; bb < 2; ++bb)
            hf[bb] = *(const bf16x8*)&h1[((bg * 2 + bb) * 16 + l16) * H1S + kt * 32 + quad * 8];
          #pragma unroll
          for (int bb = 0; bb < 2; ++bb) {
            acc[bb][0] = mfma16(wf0, hf[bb], acc[bb][0]);
            acc[bb][1] = mfma16(wf1, hf[bb], acc[bb][1]);
          }
        }
        __syncthreads();   // (H) h2c free (a0p/prev-cc reads done)
        #pragma unroll
        for (int bb = 0; bb < 2; ++bb) {
          #pragma unroll
          for (int ct = 0; ct < 2; ++ct) {
            bf16x4 p;
            #pragma unroll
            for (int r = 0; r < 4; ++r) p[r] = (__bf16)fmaxf(acc[bb][ct][r], 0.f);
            *(bf16x4*)&h2c[((bg * 2 + bb) * 16 + l16) * H2S + (ng * 2 + ct) * 16 + quad * 4] = p;
          }
        }
        __syncthreads();   // (I) h2 ready
        if (wv < 4) {
          #pragma unroll
          for (int k2 = 0; k2 < 4; ++k2) {
            bf16x8 hf2 = *(const bf16x8*)&h2c[(wv * 16 + l16) * H2S + k2 * 32 + quad * 8];
            bf16x8 wf2 = *(const bf16x8*)(W2 + ((cc * 4 + k2) * 64 + lane) * 8);
            po = mfma16(wf2, hf2, po);
          }
        }
      }
      // pose epilogue: accumulate in registers across ensembles
      if (wv < 4) {
        #pragma unroll
        for (int r = 0; r < 4; ++r) {
          int o = quad * 4 + r;
          if (o < 13)
            posacc[r] += po[r] * (sigma_t_pose[o] + 1e-8f) + mu_t_pose[o] +
                         se[(size_t)(b0 + wv * 16 + l16) * 29 + o];
        }
      }
    }
  } // e

  // ================= final writes: mean over ensembles =================
  if (wv < 4) {
    #pragma unroll
    for (int r = 0; r < 4; ++r) {
      int o = quad * 4 + r;
      if (o < 13)
        out[(size_t)(b0 + wv * 16 + l16) * 29 + o] = 0.25f * posacc[r];
    }
  }
  #pragma unroll
  for (int jj = 0; jj < 2; ++jj) {
    int idx = tid * 2 + jj, t = idx >> 4, k = idx & 15;
    out[(size_t)(b0 + t) * 29 + 13 + k] = 0.25f * legreg[jj];
  }
}

// ---------------- launch ----------------------------------------------------
extern "C" void kernel_launch(void* const* d_in, const int* in_sizes, int n_in,
                              void* d_out, int out_size, void* d_ws, size_t ws_size,
                              hipStream_t stream) {
  const float* state = (const float*)d_in[0];
  const float* act = (const float*)d_in[1];
  const float* wl0 = (const float*)d_in[2];
  const float* bl0 = (const float*)d_in[3];
  const float* wl1 = (const float*)d_in[4];
  const float* bl1 = (const float*)d_in[5];
  const float* wl2 = (const float*)d_in[6];
  const float* bl2 = (const float*)d_in[7];
  const float* wp0 = (const float*)d_in[8];
  const float* bp0 = (const float*)d_in[9];
  const float* wp1 = (const float*)d_in[10];
  const float* bp1 = (const float*)d_in[11];
  const float* wp2 = (const float*)d_in[12];
  const float* bp2 = (const float*)d_in[13];
  const float* mu_leg = (const float*)d_in[14];
  const float* sigma_leg = (const float*)d_in[15];
  const float* mu_pose = (const float*)d_in[16];
  const float* sigma_pose = (const float*)d_in[17];
  const float* mu_t_leg = (const float*)d_in[18];
  const float* sigma_t_leg = (const float*)d_in[19];
  const float* mu_t_pose = (const float*)d_in[20];
  const float* sigma_t_pose = (const float*)d_in[21];
  float* out = (float*)d_out;

  char* ws = (char*)d_ws;
  __bf16* WL0p = (__bf16*)(ws);                  // 131072
  __bf16* WL1p = (__bf16*)(ws + 131072);         // 2097152
  __bf16* WP0p = (__bf16*)(ws + 2228224);        // 131072
  __bf16* WP1p = (__bf16*)(ws + 2359296);        // 2097152
  __bf16* WP2p = (__bf16*)(ws + 4456448);        // 65536
  float* bl0f = (float*)(ws + 4521984);          // 8192
  float* bp0f = (float*)(ws + 4530176);          // 8192

  prep_kernel<<<512, 256, 0, stream>>>(wl0, wl1, wp0, wp1, wp2, bl0, bp0,
                                       mu_leg, sigma_leg, mu_pose, sigma_pose,
                                       WL0p, WL1p, WP0p, WP1p, WP2p, bl0f, bp0f);
  fused_kernel<<<256, 512, 0, stream>>>(state, act, bl1, bl2, bp1, bp2, wl2,
                                        mu_t_leg, sigma_t_leg, mu_t_pose, sigma_t_pose,
                                        WL0p, WL1p, WP0p, WP1p, WP2p,
                                        bl0f, bp0f, out);
}

// Round 4
// 678.912 us; speedup vs baseline: 1.0036x; 1.0036x over previous
//
#include <hip/hip_runtime.h>

// NPG model: E=4, B=16384, STATE=29, ACT=8, HID=512.
// R4: R3 + __launch_bounds__(512, 2). R3 spilled ~3.3KB/thread to scratch
// (437MB WRITE_SIZE) because the compiler capped VGPRs at 128 without the
// min-waves arg. Occupancy is LDS-capped at 2 waves/SIMD anyway (159KB/CU),
// so a 256-VGPR budget is free.

#define E_ 4
#define B_ 16384
#define H1S 520   // bf16 elems; 1040B row = 16B-aligned
#define H2S 136
#define A0S 40

typedef float f32x4 __attribute__((ext_vector_type(4)));
typedef __bf16 bf16x8 __attribute__((ext_vector_type(8)));
typedef __bf16 bf16x4 __attribute__((ext_vector_type(4)));

__device__ __forceinline__ f32x4 mfma16(bf16x8 a, bf16x8 b, f32x4 c) {
  return __builtin_amdgcn_mfma_f32_16x16x32_bf16(a, b, c, 0, 0, 0);
}

__device__ __forceinline__ void fmt_map(int k, int& ib, int& j) {
  if (k < 8) { ib = k >> 1; j = (k & 1) ? 2 : 0; }
  else { int k8 = k - 8; ib = k8 >> 1; j = (k8 & 1) ? 3 : 1; }
}

// packed fragment index for W(KxN): lane holds W[kt*32+quad*8+j][nt*16+l16]
__device__ __forceinline__ int pidx(int KT, int k, int n) {
  return (((n >> 4) * KT + (k >> 5)) * 64 + ((k >> 3) & 3) * 16 + (n & 15)) * 8 + (k & 7);
}

// ---------------- prep: coalesced-read pack to bf16 fragments ---------------
__global__ void prep_kernel(const float* __restrict__ wl0, const float* __restrict__ wl1,
                            const float* __restrict__ wp0, const float* __restrict__ wp1,
                            const float* __restrict__ wp2,
                            const float* __restrict__ bl0, const float* __restrict__ bp0,
                            const float* __restrict__ mu_leg, const float* __restrict__ sigma_leg,
                            const float* __restrict__ mu_pose, const float* __restrict__ sigma_pose,
                            __bf16* __restrict__ WL0p, __bf16* __restrict__ WL1p,
                            __bf16* __restrict__ WP0p, __bf16* __restrict__ WP1p,
                            __bf16* __restrict__ WP2p,
                            float* __restrict__ bl0f, float* __restrict__ bp0f)
{
  const int total = 12288 + 53248 + 1048576 + 59392 + 6144 + 1048576 + 32768 + 4096;
  for (int idx0 = blockIdx.x * blockDim.x + threadIdx.x; idx0 < total;
       idx0 += gridDim.x * blockDim.x) {
    int x = idx0;
    if (x < 12288) {
      int e = x / 3072, r = x - e * 3072, k = r >> 9, n = r & 511;
      WL0p[e * 16384 + pidx(1, k, n)] =
          (__bf16)(wl0[(e * 6 + k) * 512 + n] / (sigma_leg[k] + 1e-8f));
    } else if ((x -= 12288) < 53248) {
      int e = x / 13312, r = x - e * 13312, k = 6 + (r >> 9), n = r & 511;
      WL0p[e * 16384 + pidx(1, k, n)] = (__bf16)0.f;
    } else if ((x -= 53248) < 1048576) {
      int e = x >> 18, r = x & 262143, k = r >> 9, n = r & 511;
      WL1p[(size_t)e * 262144 + pidx(16, k, n)] = (__bf16)wl1[((size_t)(e * 512 + k)) * 512 + n];
    } else if ((x -= 1048576) < 59392) {
      int e = x / 14848, r = x - e * 14848, k = r >> 9, n = r & 511;
      WP0p[e * 16384 + pidx(1, k, n)] =
          (__bf16)(wp0[(e * 29 + k) * 512 + n] / (sigma_pose[k] + 1e-8f));
    } else if ((x -= 59392) < 6144) {
      int e = x / 1536, r = x - e * 1536, k = 29 + (r >> 9), n = r & 511;
      WP0p[e * 16384 + pidx(1, k, n)] = (__bf16)0.f;
    } else if ((x -= 6144) < 1048576) {
      int e = x >> 18, r = x & 262143, k = r >> 9, n = r & 511;
      WP1p[(size_t)e * 262144 + pidx(16, k, n)] = (__bf16)wp1[((size_t)(e * 512 + k)) * 512 + n];
    } else if ((x -= 1048576) < 32768) {
      int e = x >> 13, r = x & 8191, k = r >> 4, n = r & 15;
      WP2p[e * 8192 + pidx(16, k, n)] = (__bf16)wp2[(e * 512 + k) * 26 + n];
    } else {
      x -= 32768;  // bias folds: b0' = b0 - sum_k mu[k]/(sigma[k]+eps) * W0[k,:]
      if (x < 2048) {
        int e = x >> 9, n = x & 511;
        float s = bl0[e * 512 + n];
        #pragma unroll
        for (int k = 0; k < 6; ++k)
          s -= mu_leg[k] / (sigma_leg[k] + 1e-8f) * wl0[(e * 6 + k) * 512 + n];
        bl0f[e * 512 + n] = s;
      } else {
        x -= 2048;
        int e = x >> 9, n = x & 511;
        float s = bp0[e * 512 + n];
        for (int k = 0; k < 29; ++k)
          s -= mu_pose[k] / (sigma_pose[k] + 1e-8f) * wp0[(e * 29 + k) * 512 + n];
        bp0f[e * 512 + n] = s;
      }
    }
  }
}

// ---------------- fused model kernel ----------------------------------------
__global__ __launch_bounds__(512, 2) void fused_kernel(
    const float* __restrict__ state, const float* __restrict__ act,
    const float* __restrict__ bl1, const float* __restrict__ bl2,
    const float* __restrict__ bp1, const float* __restrict__ bp2,
    const float* __restrict__ wl2,  // fp32, used directly by VALU layer2
    const float* __restrict__ mu_t_leg, const float* __restrict__ sigma_t_leg,
    const float* __restrict__ mu_t_pose, const float* __restrict__ sigma_t_pose,
    const __bf16* __restrict__ WL0p, const __bf16* __restrict__ WL1p,
    const __bf16* __restrict__ WP0p, const __bf16* __restrict__ WP1p,
    const __bf16* __restrict__ WP2p,
    const float* __restrict__ bl0f, const float* __restrict__ bp0f,
    float* __restrict__ out)
{
  __shared__ alignas(16) __bf16 h1[128 * H1S];   // 133120 B
  __shared__ alignas(16) __bf16 h2c[64 * H2S];   // 17408 B (union: a0 staging)
  __shared__ float ldiff[64][16];                // 4096 B
  __shared__ float legpart[128 * 16];            // 8192 B
  __bf16* a0s = h2c;                             // leg a0 128x40=10240B fits

  const int tid = threadIdx.x;
  const int wv = tid >> 6;
  const int lane = tid & 63;
  const int quad = lane >> 4;
  const int l16 = lane & 15;
  const int b0 = blockIdx.x * 64;

  f32x4 posacc = {0.f, 0.f, 0.f, 0.f};
  float legreg[2] = {0.f, 0.f};

  for (int e = 0; e < E_; ++e) {
    const float* se = state + (size_t)e * B_ * 29;
    const float* ae = act + (size_t)e * B_ * 8;

    // ================= leg MLP: 2 passes of 128 leg rows =================
    {
      const __bf16* W0 = WL0p + e * 16384;
      const __bf16* W1 = WL1p + (size_t)e * 262144;
      const float* b0v = bl0f + e * 512;
      const float* b1v = bl1 + e * 512;
      const float* w2l = wl2 + (size_t)e * 4096;  // 512x8 fp32

      for (int half = 0; half < 2; ++half) {
        __syncthreads();   // (A) a0s / legpart regions free
        for (int i = tid; i < 128 * 32; i += 512) {
          int r = i >> 5, c = i & 31;
          float v = 0.f;
          if (c < 6) {
            int ib = r >> 5;
            int b = b0 + half * 32 + (r & 31);
            const float* sp = se + (size_t)b * 29;
            if (c == 0) v = sp[13 + 2 * ib];
            else if (c == 1) v = sp[21 + 2 * ib];
            else if (c == 2) v = sp[14 + 2 * ib];
            else if (c == 3) v = sp[22 + 2 * ib];
            else if (c == 4) v = ae[(size_t)b * 8 + 2 * ib];
            else v = ae[(size_t)b * 8 + 2 * ib + 1];
          }
          a0s[r * A0S + c] = (__bf16)v;
        }
        __syncthreads();   // (B) a0 ready

        // ---- layer0 (transposed): h1[batch][n], packed b64 writes
        {
          bf16x8 wfr[4]; f32x4 bias[4];
          #pragma unroll
          for (int i = 0; i < 4; ++i) {
            int nt = wv * 4 + i;
            wfr[i] = *(const bf16x8*)(W0 + (nt * 64 + lane) * 8);
            bias[i] = *(const f32x4*)(b0v + nt * 16 + quad * 4);
          }
          for (int bt = 0; bt < 8; ++bt) {
            bf16x8 xfr = *(const bf16x8*)&a0s[(bt * 16 + l16) * A0S + quad * 8];
            #pragma unroll
            for (int i = 0; i < 4; ++i) {
              f32x4 acc = mfma16(wfr[i], xfr, bias[i]);
              bf16x4 p;
              #pragma unroll
              for (int r = 0; r < 4; ++r) p[r] = (__bf16)fmaxf(acc[r], 0.f);
              *(bf16x4*)&h1[(bt * 16 + l16) * H1S + (wv * 4 + i) * 16 + quad * 4] = p;
            }
          }
        }
        __syncthreads();   // (C) h1 ready

        // ---- layer1 (transposed) + VALU layer2 (o<4) from regs
        const int ng = wv >> 1;   // 2 n-tiles each
        const int bg = wv & 1;    // 4 batch-tiles each
        f32x4 po[4] = {{0,0,0,0},{0,0,0,0},{0,0,0,0},{0,0,0,0}};
        for (int cc = 0; cc < 4; ++cc) {
          f32x4 acc[4][2];
          #pragma unroll
          for (int ct = 0; ct < 2; ++ct) {
            f32x4 bias = *(const f32x4*)(b1v + cc * 128 + (ng * 2 + ct) * 16 + quad * 4);
            #pragma unroll
            for (int bb = 0; bb < 4; ++bb) acc[bb][ct] = bias;
          }
          const int ntb = cc * 8 + ng * 2;
          #pragma unroll 4
          for (int kt = 0; kt < 16; ++kt) {
            bf16x8 wf0 = *(const bf16x8*)(W1 + ((size_t)((ntb + 0) * 16 + kt) * 64 + lane) * 8);
            bf16x8 wf1 = *(const bf16x8*)(W1 + ((size_t)((ntb + 1) * 16 + kt) * 64 + lane) * 8);
            bf16x8 hf[4];
            #pragma unroll
            for (int bb = 0; bb < 4; ++bb)
              hf[bb] = *(const bf16x8*)&h1[((bg * 4 + bb) * 16 + l16) * H1S + kt * 32 + quad * 8];
            #pragma unroll
            for (int bb = 0; bb < 4; ++bb) {
              acc[bb][0] = mfma16(wf0, hf[bb], acc[bb][0]);
              acc[bb][1] = mfma16(wf1, hf[bb], acc[bb][1]);
            }
          }
          // layer2 partials: po[bb][o] += relu(h2) * W2[n][o], o=0..3
          #pragma unroll
          for (int ct = 0; ct < 2; ++ct) {
            #pragma unroll
            for (int r = 0; r < 4; ++r) {
              int n = (ntb + ct) * 16 + quad * 4 + r;
              f32x4 w2v = *(const f32x4*)(w2l + n * 8);
              #pragma unroll
              for (int bb = 0; bb < 4; ++bb) {
                float h = fmaxf(acc[bb][ct][r], 0.f);
                po[bb] += h * w2v;
              }
            }
          }
        }
        // quad-reduce (n-dim lives on quads; batch l16 preserved)
        #pragma unroll
        for (int bb = 0; bb < 4; ++bb) {
          #pragma unroll
          for (int c = 0; c < 4; ++c) {
            po[bb][c] += __shfl_xor(po[bb][c], 16);
            po[bb][c] += __shfl_xor(po[bb][c], 32);
          }
        }
        if (quad == 0) {
          #pragma unroll
          for (int bb = 0; bb < 4; ++bb)
            *(f32x4*)&legpart[((bg * 4 + bb) * 16 + l16) * 16 + ng * 4] = po[bb];
        }
        __syncthreads();   // (D) legpart ready
        {
          int L = tid >> 2, o = tid & 3;
          float s = legpart[L * 16 + o] + legpart[L * 16 + 4 + o] +
                    legpart[L * 16 + 8 + o] + legpart[L * 16 + 12 + o] + bl2[e * 8 + o];
          s = s * (sigma_t_leg[o] + 1e-8f) + mu_t_leg[o];
          ldiff[half * 32 + (L & 31)][(L >> 5) * 4 + o] = s;
        }
      } // half
    }
    __syncthreads();       // (E) ldiff ready

    // ================= pose MLP: 64 rows =================
    for (int i = tid; i < 64 * 32; i += 512) {
      int t = i >> 5, c = i & 31;
      float v = 0.f;
      if (c < 13) v = se[(size_t)(b0 + t) * 29 + c];
      else if (c < 29) { int ib, j; fmt_map(c - 13, ib, j); v = ldiff[t][ib * 4 + j]; }
      a0s[t * A0S + c] = (__bf16)v;
    }
    {  // legs output accumulation (registers)
      #pragma unroll
      for (int jj = 0; jj < 2; ++jj) {
        int idx = tid * 2 + jj, t = idx >> 4, k = idx & 15;
        int ib, j; fmt_map(k, ib, j);
        legreg[jj] += se[(size_t)(b0 + t) * 29 + 13 + k] + ldiff[t][ib * 4 + j];
      }
    }
    __syncthreads();       // (F) a0p ready

    // ---- pose layer0
    {
      const __bf16* W0 = WP0p + e * 16384;
      const float* b0v = bp0f + e * 512;
      bf16x8 wfr[4]; f32x4 bias[4];
      #pragma unroll
      for (int i = 0; i < 4; ++i) {
        int nt = wv * 4 + i;
        wfr[i] = *(const bf16x8*)(W0 + (nt * 64 + lane) * 8);
        bias[i] = *(const f32x4*)(b0v + nt * 16 + quad * 4);
      }
      for (int bt = 0; bt < 4; ++bt) {
        bf16x8 xfr = *(const bf16x8*)&a0s[(bt * 16 + l16) * A0S + quad * 8];
        #pragma unroll
        for (int i = 0; i < 4; ++i) {
          f32x4 acc = mfma16(wfr[i], xfr, bias[i]);
          bf16x4 p;
          #pragma unroll
          for (int r = 0; r < 4; ++r) p[r] = (__bf16)fmaxf(acc[r], 0.f);
          *(bf16x4*)&h1[(bt * 16 + l16) * H1S + (wv * 4 + i) * 16 + quad * 4] = p;
        }
      }
    }
    __syncthreads();       // (G) h1 ready (a0p reads done)

    // ---- pose layer1 + MFMA layer2 via h2c
    {
      const __bf16* W1 = WP1p + (size_t)e * 262144;
      const __bf16* W2 = WP2p + e * 8192;
      const float* b1v = bp1 + e * 512;
      const int ng = wv >> 1;   // 2 n-tiles
      const int bg = wv & 1;    // 2 batch-tiles
      f32x4 po;
      #pragma unroll
      for (int r = 0; r < 4; ++r) po[r] = bp2[e * 26 + quad * 4 + r];

      for (int cc = 0; cc < 4; ++cc) {
        f32x4 acc[2][2];
        #pragma unroll
        for (int ct = 0; ct < 2; ++ct) {
          f32x4 bias = *(const f32x4*)(b1v + cc * 128 + (ng * 2 + ct) * 16 + quad * 4);
          #pragma unroll
          for (int bb = 0; bb < 2; ++bb) acc[bb][ct] = bias;
        }
        const int ntb = cc * 8 + ng * 2;
        #pragma unroll 4
        for (int kt = 0; kt < 16; ++kt) {
          bf16x8 wf0 = *(const bf16x8*)(W1 + ((size_t)((ntb + 0) * 16 + kt) * 64 + lane) * 8);
          bf16x8 wf1 = *(const bf16x8*)(W1 + ((size_t)((ntb + 1) * 16 + kt) * 64 + lane) * 8);
          bf16x8 hf[2];
          #pragma unroll
          for (int bb = 0; bb < 2; ++bb)
            hf[bb] = *(const bf16x8*)&h1[((bg * 2 + bb) * 16 + l16) * H1S + kt * 32 + quad * 8];
          #pragma unroll
          for (int bb = 0; bb < 2; ++bb) {
            acc[bb][0] = mfma16(wf0, hf[bb], acc[bb][0]);
            acc[bb][1] = mfma16(wf1, hf[bb], acc[bb][1]);
          }
        }
        __syncthreads();   // (H) h2c free (a0p/prev-cc reads done)
        #pragma unroll
        for (int bb = 0; bb < 2; ++bb) {
          #pragma unroll
          for (int ct = 0; ct < 2; ++ct) {
            bf16x4 p;
            #pragma unroll
            for (int r = 0; r < 4; ++r) p[r] = (__bf16)fmaxf(acc[bb][ct][r], 0.f);
            *(bf16x4*)&h2c[((bg * 2 + bb) * 16 + l16) * H2S + (ng * 2 + ct) * 16 + quad * 4] = p;
          }
        }
        __syncthreads();   // (I) h2 ready
        if (wv < 4) {
          #pragma unroll
          for (int k2 = 0; k2 < 4; ++k2) {
            bf16x8 hf2 = *(const bf16x8*)&h2c[(wv * 16 + l16) * H2S + k2 * 32 + quad * 8];
            bf16x8 wf2 = *(const bf16x8*)(W2 + ((cc * 4 + k2) * 64 + lane) * 8);
            po = mfma16(wf2, hf2, po);
          }
        }
      }
      // pose epilogue: accumulate in registers across ensembles
      if (wv < 4) {
        #pragma unroll
        for (int r = 0; r < 4; ++r) {
          int o = quad * 4 + r;
          if (o < 13)
            posacc[r] += po[r] * (sigma_t_pose[o] + 1e-8f) + mu_t_pose[o] +
                         se[(size_t)(b0 + wv * 16 + l16) * 29 + o];
        }
      }
    }
  } // e

  // ================= final writes: mean over ensembles =================
  if (wv < 4) {
    #pragma unroll
    for (int r = 0; r < 4; ++r) {
      int o = quad * 4 + r;
      if (o < 13)
        out[(size_t)(b0 + wv * 16 + l16) * 29 + o] = 0.25f * posacc[r];
    }
  }
  #pragma unroll
  for (int jj = 0; jj < 2; ++jj) {
    int idx = tid * 2 + jj, t = idx >> 4, k = idx & 15;
    out[(size_t)(b0 + t) * 29 + 13 + k] = 0.25f * legreg[jj];
  }
}

// ---------------- launch ----------------------------------------------------
extern "C" void kernel_launch(void* const* d_in, const int* in_sizes, int n_in,
                              void* d_out, int out_size, void* d_ws, size_t ws_size,
                              hipStream_t stream) {
  const float* state = (const float*)d_in[0];
  const float* act = (const float*)d_in[1];
  const float* wl0 = (const float*)d_in[2];
  const float* bl0 = (const float*)d_in[3];
  const float* wl1 = (const float*)d_in[4];
  const float* bl1 = (const float*)d_in[5];
  const float* wl2 = (const float*)d_in[6];
  const float* bl2 = (const float*)d_in[7];
  const float* wp0 = (const float*)d_in[8];
  const float* bp0 = (const float*)d_in[9];
  const float* wp1 = (const float*)d_in[10];
  const float* bp1 = (const float*)d_in[11];
  const float* wp2 = (const float*)d_in[12];
  const float* bp2 = (const float*)d_in[13];
  const float* mu_leg = (const float*)d_in[14];
  const float* sigma_leg = (const float*)d_in[15];
  const float* mu_pose = (const float*)d_in[16];
  const float* sigma_pose = (const float*)d_in[17];
  const float* mu_t_leg = (const float*)d_in[18];
  const float* sigma_t_leg = (const float*)d_in[19];
  const float* mu_t_pose = (const float*)d_in[20];
  const float* sigma_t_pose = (const float*)d_in[21];
  float* out = (float*)d_out;

  char* ws = (char*)d_ws;
  __bf16* WL0p = (__bf16*)(ws);                  // 131072
  __bf16* WL1p = (__bf16*)(ws + 131072);         // 2097152
  __bf16* WP0p = (__bf16*)(ws + 2228224);        // 131072
  __bf16* WP1p = (__bf16*)(ws + 2359296);        // 2097152
  __bf16* WP2p = (__bf16*)(ws + 4456448);        // 65536
  float* bl0f = (float*)(ws + 4521984);          // 8192
  float* bp0f = (float*)(ws + 4530176);          // 8192

  prep_kernel<<<512, 256, 0, stream>>>(wl0, wl1, wp0, wp1, wp2, bl0, bp0,
                                       mu_leg, sigma_leg, mu_pose, sigma_pose,
                                       WL0p, WL1p, WP0p, WP1p, WP2p, bl0f, bp0f);
  fused_kernel<<<256, 512, 0, stream>>>(state, act, bl1, bl2, bp1, bp2, wl2,
                                        mu_t_leg, sigma_t_leg, mu_t_pose, sigma_t_pose,
                                        WL0p, WL1p, WP0p, WP1p, WP2p,
                                        bl0f, bp0f, out);
}

// Round 5
// 609.884 us; speedup vs baseline: 1.1172x; 1.1132x over previous
//
#include <hip/hip_runtime.h>

// NPG model: E=4, B=16384, STATE=29, ACT=8, HID=512.
// R5: de-spill. R3/R4 spilled ~3.3KB/thread (437MB scratch traffic): HIP's
// 2nd launch_bounds arg acts as min-BLOCKS/CU -> (512,2) = 4 waves/EU = 128
// VGPR cap, while unroll-4 software pipelining needed ~200. Fixes:
// (1) __launch_bounds__(512,1) -> 256-VGPR budget (occupancy is LDS-capped
//     at 1 block/CU anyway); (2) unroll 2 (not 4) on kt loops; (3) leg-layer2
//     partials retired to LDS per-cc (wave-exclusive slots, no extra barriers)
//     instead of 16 VGPRs live across the cc loop.

#define E_ 4
#define B_ 16384
#define H1S 520   // bf16 elems; 1040B row = 16B-aligned
#define H2S 136
#define A0S 40

typedef float f32x4 __attribute__((ext_vector_type(4)));
typedef __bf16 bf16x8 __attribute__((ext_vector_type(8)));
typedef __bf16 bf16x4 __attribute__((ext_vector_type(4)));

__device__ __forceinline__ f32x4 mfma16(bf16x8 a, bf16x8 b, f32x4 c) {
  return __builtin_amdgcn_mfma_f32_16x16x32_bf16(a, b, c, 0, 0, 0);
}

__device__ __forceinline__ void fmt_map(int k, int& ib, int& j) {
  if (k < 8) { ib = k >> 1; j = (k & 1) ? 2 : 0; }
  else { int k8 = k - 8; ib = k8 >> 1; j = (k8 & 1) ? 3 : 1; }
}

// packed fragment index for W(KxN): lane holds W[kt*32+quad*8+j][nt*16+l16]
__device__ __forceinline__ int pidx(int KT, int k, int n) {
  return (((n >> 4) * KT + (k >> 5)) * 64 + ((k >> 3) & 3) * 16 + (n & 15)) * 8 + (k & 7);
}

// ---------------- prep: coalesced-read pack to bf16 fragments ---------------
__global__ void prep_kernel(const float* __restrict__ wl0, const float* __restrict__ wl1,
                            const float* __restrict__ wp0, const float* __restrict__ wp1,
                            const float* __restrict__ wp2,
                            const float* __restrict__ bl0, const float* __restrict__ bp0,
                            const float* __restrict__ mu_leg, const float* __restrict__ sigma_leg,
                            const float* __restrict__ mu_pose, const float* __restrict__ sigma_pose,
                            __bf16* __restrict__ WL0p, __bf16* __restrict__ WL1p,
                            __bf16* __restrict__ WP0p, __bf16* __restrict__ WP1p,
                            __bf16* __restrict__ WP2p,
                            float* __restrict__ bl0f, float* __restrict__ bp0f)
{
  const int total = 12288 + 53248 + 1048576 + 59392 + 6144 + 1048576 + 32768 + 4096;
  for (int idx0 = blockIdx.x * blockDim.x + threadIdx.x; idx0 < total;
       idx0 += gridDim.x * blockDim.x) {
    int x = idx0;
    if (x < 12288) {
      int e = x / 3072, r = x - e * 3072, k = r >> 9, n = r & 511;
      WL0p[e * 16384 + pidx(1, k, n)] =
          (__bf16)(wl0[(e * 6 + k) * 512 + n] / (sigma_leg[k] + 1e-8f));
    } else if ((x -= 12288) < 53248) {
      int e = x / 13312, r = x - e * 13312, k = 6 + (r >> 9), n = r & 511;
      WL0p[e * 16384 + pidx(1, k, n)] = (__bf16)0.f;
    } else if ((x -= 53248) < 1048576) {
      int e = x >> 18, r = x & 262143, k = r >> 9, n = r & 511;
      WL1p[(size_t)e * 262144 + pidx(16, k, n)] = (__bf16)wl1[((size_t)(e * 512 + k)) * 512 + n];
    } else if ((x -= 1048576) < 59392) {
      int e = x / 14848, r = x - e * 14848, k = r >> 9, n = r & 511;
      WP0p[e * 16384 + pidx(1, k, n)] =
          (__bf16)(wp0[(e * 29 + k) * 512 + n] / (sigma_pose[k] + 1e-8f));
    } else if ((x -= 59392) < 6144) {
      int e = x / 1536, r = x - e * 1536, k = 29 + (r >> 9), n = r & 511;
      WP0p[e * 16384 + pidx(1, k, n)] = (__bf16)0.f;
    } else if ((x -= 6144) < 1048576) {
      int e = x >> 18, r = x & 262143, k = r >> 9, n = r & 511;
      WP1p[(size_t)e * 262144 + pidx(16, k, n)] = (__bf16)wp1[((size_t)(e * 512 + k)) * 512 + n];
    } else if ((x -= 1048576) < 32768) {
      int e = x >> 13, r = x & 8191, k = r >> 4, n = r & 15;
      WP2p[e * 8192 + pidx(16, k, n)] = (__bf16)wp2[(e * 512 + k) * 26 + n];
    } else {
      x -= 32768;  // bias folds: b0' = b0 - sum_k mu[k]/(sigma[k]+eps) * W0[k,:]
      if (x < 2048) {
        int e = x >> 9, n = x & 511;
        float s = bl0[e * 512 + n];
        #pragma unroll
        for (int k = 0; k < 6; ++k)
          s -= mu_leg[k] / (sigma_leg[k] + 1e-8f) * wl0[(e * 6 + k) * 512 + n];
        bl0f[e * 512 + n] = s;
      } else {
        x -= 2048;
        int e = x >> 9, n = x & 511;
        float s = bp0[e * 512 + n];
        for (int k = 0; k < 29; ++k)
          s -= mu_pose[k] / (sigma_pose[k] + 1e-8f) * wp0[(e * 29 + k) * 512 + n];
        bp0f[e * 512 + n] = s;
      }
    }
  }
}

// ---------------- fused model kernel ----------------------------------------
__global__ __launch_bounds__(512, 1) void fused_kernel(
    const float* __restrict__ state, const float* __restrict__ act,
    const float* __restrict__ bl1, const float* __restrict__ bl2,
    const float* __restrict__ bp1, const float* __restrict__ bp2,
    const float* __restrict__ wl2,  // fp32, used directly by VALU layer2
    const float* __restrict__ mu_t_leg, const float* __restrict__ sigma_t_leg,
    const float* __restrict__ mu_t_pose, const float* __restrict__ sigma_t_pose,
    const __bf16* __restrict__ WL0p, const __bf16* __restrict__ WL1p,
    const __bf16* __restrict__ WP0p, const __bf16* __restrict__ WP1p,
    const __bf16* __restrict__ WP2p,
    const float* __restrict__ bl0f, const float* __restrict__ bp0f,
    float* __restrict__ out)
{
  __shared__ alignas(16) __bf16 h1[128 * H1S];   // 133120 B
  __shared__ alignas(16) __bf16 h2c[64 * H2S];   // 17408 B (union: a0 staging)
  __shared__ float ldiff[64][16];                // 4096 B
  __shared__ float legpart[128 * 16];            // 8192 B
  __bf16* a0s = h2c;                             // leg a0 128x40=10240B fits

  const int tid = threadIdx.x;
  const int wv = tid >> 6;
  const int lane = tid & 63;
  const int quad = lane >> 4;
  const int l16 = lane & 15;
  const int b0 = blockIdx.x * 64;

  f32x4 posacc = {0.f, 0.f, 0.f, 0.f};
  float legreg[2] = {0.f, 0.f};

  for (int e = 0; e < E_; ++e) {
    const float* se = state + (size_t)e * B_ * 29;
    const float* ae = act + (size_t)e * B_ * 8;

    // ================= leg MLP: 2 passes of 128 leg rows =================
    {
      const __bf16* W0 = WL0p + e * 16384;
      const __bf16* W1 = WL1p + (size_t)e * 262144;
      const float* b0v = bl0f + e * 512;
      const float* b1v = bl1 + e * 512;
      const float* w2l = wl2 + (size_t)e * 4096;  // 512x8 fp32

      for (int half = 0; half < 2; ++half) {
        __syncthreads();   // (A) a0s / legpart regions free
        for (int i = tid; i < 128 * 32; i += 512) {
          int r = i >> 5, c = i & 31;
          float v = 0.f;
          if (c < 6) {
            int ib = r >> 5;
            int b = b0 + half * 32 + (r & 31);
            const float* sp = se + (size_t)b * 29;
            if (c == 0) v = sp[13 + 2 * ib];
            else if (c == 1) v = sp[21 + 2 * ib];
            else if (c == 2) v = sp[14 + 2 * ib];
            else if (c == 3) v = sp[22 + 2 * ib];
            else if (c == 4) v = ae[(size_t)b * 8 + 2 * ib];
            else v = ae[(size_t)b * 8 + 2 * ib + 1];
          }
          a0s[r * A0S + c] = (__bf16)v;
        }
        __syncthreads();   // (B) a0 ready

        // ---- layer0 (transposed): h1[batch][n], packed b64 writes
        {
          bf16x8 wfr[4]; f32x4 bias[4];
          #pragma unroll
          for (int i = 0; i < 4; ++i) {
            int nt = wv * 4 + i;
            wfr[i] = *(const bf16x8*)(W0 + (nt * 64 + lane) * 8);
            bias[i] = *(const f32x4*)(b0v + nt * 16 + quad * 4);
          }
          for (int bt = 0; bt < 8; ++bt) {
            bf16x8 xfr = *(const bf16x8*)&a0s[(bt * 16 + l16) * A0S + quad * 8];
            #pragma unroll
            for (int i = 0; i < 4; ++i) {
              f32x4 acc = mfma16(wfr[i], xfr, bias[i]);
              bf16x4 p;
              #pragma unroll
              for (int r = 0; r < 4; ++r) p[r] = (__bf16)fmaxf(acc[r], 0.f);
              *(bf16x4*)&h1[(bt * 16 + l16) * H1S + (wv * 4 + i) * 16 + quad * 4] = p;
            }
          }
        }
        __syncthreads();   // (C) h1 ready

        // ---- layer1 (transposed) + VALU layer2 (o<4), partials to LDS/cc
        const int ng = wv >> 1;   // 2 n-tiles each
        const int bg = wv & 1;    // 4 batch-tiles each
        for (int cc = 0; cc < 4; ++cc) {
          f32x4 acc[4][2];
          #pragma unroll
          for (int ct = 0; ct < 2; ++ct) {
            f32x4 bias = *(const f32x4*)(b1v + cc * 128 + (ng * 2 + ct) * 16 + quad * 4);
            #pragma unroll
            for (int bb = 0; bb < 4; ++bb) acc[bb][ct] = bias;
          }
          const int ntb = cc * 8 + ng * 2;
          #pragma unroll 2
          for (int kt = 0; kt < 16; ++kt) {
            bf16x8 wf0 = *(const bf16x8*)(W1 + ((size_t)((ntb + 0) * 16 + kt) * 64 + lane) * 8);
            bf16x8 wf1 = *(const bf16x8*)(W1 + ((size_t)((ntb + 1) * 16 + kt) * 64 + lane) * 8);
            bf16x8 hf[4];
            #pragma unroll
            for (int bb = 0; bb < 4; ++bb)
              hf[bb] = *(const bf16x8*)&h1[((bg * 4 + bb) * 16 + l16) * H1S + kt * 32 + quad * 8];
            #pragma unroll
            for (int bb = 0; bb < 4; ++bb) {
              acc[bb][0] = mfma16(wf0, hf[bb], acc[bb][0]);
              acc[bb][1] = mfma16(wf1, hf[bb], acc[bb][1]);
            }
          }
          // layer2 partials for this cc: po[bb][o] = sum_n relu(h2)*W2[n][o]
          #pragma unroll
          for (int bb = 0; bb < 4; ++bb) {
            f32x4 po = {0.f, 0.f, 0.f, 0.f};
            #pragma unroll
            for (int ct = 0; ct < 2; ++ct) {
              #pragma unroll
              for (int r = 0; r < 4; ++r) {
                int n = (ntb + ct) * 16 + quad * 4 + r;
                f32x4 w2v = *(const f32x4*)(w2l + n * 8);
                po += fmaxf(acc[bb][ct][r], 0.f) * w2v;
              }
            }
            #pragma unroll
            for (int c = 0; c < 4; ++c) {
              po[c] += __shfl_xor(po[c], 16);
              po[c] += __shfl_xor(po[c], 32);
            }
            if (quad == 0) {   // wave-exclusive slot: rows bg*64+.., cols ng*4+..
              float* slot = &legpart[((bg * 4 + bb) * 16 + l16) * 16 + ng * 4];
              if (cc == 0) *(f32x4*)slot = po;
              else         *(f32x4*)slot = *(const f32x4*)slot + po;
            }
          }
        }
        __syncthreads();   // (D) legpart ready
        {
          int L = tid >> 2, o = tid & 3;
          float s = legpart[L * 16 + o] + legpart[L * 16 + 4 + o] +
                    legpart[L * 16 + 8 + o] + legpart[L * 16 + 12 + o] + bl2[e * 8 + o];
          s = s * (sigma_t_leg[o] + 1e-8f) + mu_t_leg[o];
          ldiff[half * 32 + (L & 31)][(L >> 5) * 4 + o] = s;
        }
      } // half
    }
    __syncthreads();       // (E) ldiff ready

    // ================= pose MLP: 64 rows =================
    for (int i = tid; i < 64 * 32; i += 512) {
      int t = i >> 5, c = i & 31;
      float v = 0.f;
      if (c < 13) v = se[(size_t)(b0 + t) * 29 + c];
      else if (c < 29) { int ib, j; fmt_map(c - 13, ib, j); v = ldiff[t][ib * 4 + j]; }
      a0s[t * A0S + c] = (__bf16)v;
    }
    {  // legs output accumulation (registers)
      #pragma unroll
      for (int jj = 0; jj < 2; ++jj) {
        int idx = tid * 2 + jj, t = idx >> 4, k = idx & 15;
        int ib, j; fmt_map(k, ib, j);
        legreg[jj] += se[(size_t)(b0 + t) * 29 + 13 + k] + ldiff[t][ib * 4 + j];
      }
    }
    __syncthreads();       // (F) a0p ready

    // ---- pose layer0
    {
      const __bf16* W0 = WP0p + e * 16384;
      const float* b0v = bp0f + e * 512;
      bf16x8 wfr[4]; f32x4 bias[4];
      #pragma unroll
      for (int i = 0; i < 4; ++i) {
        int nt = wv * 4 + i;
        wfr[i] = *(const bf16x8*)(W0 + (nt * 64 + lane) * 8);
        bias[i] = *(const f32x4*)(b0v + nt * 16 + quad * 4);
      }
      for (int bt = 0; bt < 4; ++bt) {
        bf16x8 xfr = *(const bf16x8*)&a0s[(bt * 16 + l16) * A0S + quad * 8];
        #pragma unroll
        for (int i = 0; i < 4; ++i) {
          f32x4 acc = mfma16(wfr[i], xfr, bias[i]);
          bf16x4 p;
          #pragma unroll
          for (int r = 0; r < 4; ++r) p[r] = (__bf16)fmaxf(acc[r], 0.f);
          *(bf16x4*)&h1[(bt * 16 + l16) * H1S + (wv * 4 + i) * 16 + quad * 4] = p;
        }
      }
    }
    __syncthreads();       // (G) h1 ready (a0p reads done)

    // ---- pose layer1 + MFMA layer2 via h2c
    {
      const __bf16* W1 = WP1p + (size_t)e * 262144;
      const __bf16* W2 = WP2p + e * 8192;
      const float* b1v = bp1 + e * 512;
      const int ng = wv >> 1;   // 2 n-tiles
      const int bg = wv & 1;    // 2 batch-tiles
      f32x4 po;
      #pragma unroll
      for (int r = 0; r < 4; ++r) po[r] = bp2[e * 26 + quad * 4 + r];

      for (int cc = 0; cc < 4; ++cc) {
        f32x4 acc[2][2];
        #pragma unroll
        for (int ct = 0; ct < 2; ++ct) {
          f32x4 bias = *(const f32x4*)(b1v + cc * 128 + (ng * 2 + ct) * 16 + quad * 4);
          #pragma unroll
          for (int bb = 0; bb < 2; ++bb) acc[bb][ct] = bias;
        }
        const int ntb = cc * 8 + ng * 2;
        #pragma unroll 2
        for (int kt = 0; kt < 16; ++kt) {
          bf16x8 wf0 = *(const bf16x8*)(W1 + ((size_t)((ntb + 0) * 16 + kt) * 64 + lane) * 8);
          bf16x8 wf1 = *(const bf16x8*)(W1 + ((size_t)((ntb + 1) * 16 + kt) * 64 + lane) * 8);
          bf16x8 hf[2];
          #pragma unroll
          for (int bb = 0; bb < 2; ++bb)
            hf[bb] = *(const bf16x8*)&h1[((bg * 2 + bb) * 16 + l16) * H1S + kt * 32 + quad * 8];
          #pragma unroll
          for (int bb = 0; bb < 2; ++bb) {
            acc[bb][0] = mfma16(wf0, hf[bb], acc[bb][0]);
            acc[bb][1] = mfma16(wf1, hf[bb], acc[bb][1]);
          }
        }
        __syncthreads();   // (H) h2c free (a0p/prev-cc reads done)
        #pragma unroll
        for (int bb = 0; bb < 2; ++bb) {
          #pragma unroll
          for (int ct = 0; ct < 2; ++ct) {
            bf16x4 p;
            #pragma unroll
            for (int r = 0; r < 4; ++r) p[r] = (__bf16)fmaxf(acc[bb][ct][r], 0.f);
            *(bf16x4*)&h2c[((bg * 2 + bb) * 16 + l16) * H2S + (ng * 2 + ct) * 16 + quad * 4] = p;
          }
        }
        __syncthreads();   // (I) h2 ready
        if (wv < 4) {
          #pragma unroll
          for (int k2 = 0; k2 < 4; ++k2) {
            bf16x8 hf2 = *(const bf16x8*)&h2c[(wv * 16 + l16) * H2S + k2 * 32 + quad * 8];
            bf16x8 wf2 = *(const bf16x8*)(W2 + ((cc * 4 + k2) * 64 + lane) * 8);
            po = mfma16(wf2, hf2, po);
          }
        }
      }
      // pose epilogue: accumulate in registers across ensembles
      if (wv < 4) {
        #pragma unroll
        for (int r = 0; r < 4; ++r) {
          int o = quad * 4 + r;
          if (o < 13)
            posacc[r] += po[r] * (sigma_t_pose[o] + 1e-8f) + mu_t_pose[o] +
                         se[(size_t)(b0 + wv * 16 + l16) * 29 + o];
        }
      }
    }
  } // e

  // ================= final writes: mean over ensembles =================
  if (wv < 4) {
    #pragma unroll
    for (int r = 0; r < 4; ++r) {
      int o = quad * 4 + r;
      if (o < 13)
        out[(size_t)(b0 + wv * 16 + l16) * 29 + o] = 0.25f * posacc[r];
    }
  }
  #pragma unroll
  for (int jj = 0; jj < 2; ++jj) {
    int idx = tid * 2 + jj, t = idx >> 4, k = idx & 15;
    out[(size_t)(b0 + t) * 29 + 13 + k] = 0.25f * legreg[jj];
  }
}

// ---------------- launch ----------------------------------------------------
extern "C" void kernel_launch(void* const* d_in, const int* in_sizes, int n_in,
                              void* d_out, int out_size, void* d_ws, size_t ws_size,
                              hipStream_t stream) {
  const float* state = (const float*)d_in[0];
  const float* act = (const float*)d_in[1];
  const float* wl0 = (const float*)d_in[2];
  const float* bl0 = (const float*)d_in[3];
  const float* wl1 = (const float*)d_in[4];
  const float* bl1 = (const float*)d_in[5];
  const float* wl2 = (const float*)d_in[6];
  const float* bl2 = (const float*)d_in[7];
  const float* wp0 = (const float*)d_in[8];
  const float* bp0 = (const float*)d_in[9];
  const float* wp1 = (const float*)d_in[10];
  const float* bp1 = (const float*)d_in[11];
  const float* wp2 = (const float*)d_in[12];
  const float* bp2 = (const float*)d_in[13];
  const float* mu_leg = (const float*)d_in[14];
  const float* sigma_leg = (const float*)d_in[15];
  const float* mu_pose = (const float*)d_in[16];
  const float* sigma_pose = (const float*)d_in[17];
  const float* mu_t_leg = (const float*)d_in[18];
  const float* sigma_t_leg = (const float*)d_in[19];
  const float* mu_t_pose = (const float*)d_in[20];
  const float* sigma_t_pose = (const float*)d_in[21];
  float* out = (float*)d_out;

  char* ws = (char*)d_ws;
  __bf16* WL0p = (__bf16*)(ws);                  // 131072
  __bf16* WL1p = (__bf16*)(ws + 131072);         // 2097152
  __bf16* WP0p = (__bf16*)(ws + 2228224);        // 131072
  __bf16* WP1p = (__bf16*)(ws + 2359296);        // 2097152
  __bf16* WP2p = (__bf16*)(ws + 4456448);        // 65536
  float* bl0f = (float*)(ws + 4521984);          // 8192
  float* bp0f = (float*)(ws + 4530176);          // 8192

  prep_kernel<<<512, 256, 0, stream>>>(wl0, wl1, wp0, wp1, wp2, bl0, bp0,
                                       mu_leg, sigma_leg, mu_pose, sigma_pose,
                                       WL0p, WL1p, WP0p, WP1p, WP2p, bl0f, bp0f);
  fused_kernel<<<256, 512, 0, stream>>>(state, act, bl1, bl2, bp1, bp2, wl2,
                                        mu_t_leg, sigma_t_leg, mu_t_pose, sigma_t_pose,
                                        WL0p, WL1p, WP0p, WP1p, WP2p,
                                        bl0f, bp0f, out);
}

// Round 6
// 473.231 us; speedup vs baseline: 1.4399x; 1.2888x over previous
//
#include <hip/hip_runtime.h>

// NPG model: E=4, B=16384, STATE=29, ACT=8, HID=512.
// R6: de-spill by construction. R3-R5's VALU leg-layer2 read the layer1 MFMA
// accumulators with VALU ops inside the hot loop, forcing them into the arch-
// VGPR half of the unified file (128) -> 1.4-3.3KB/thread scratch. R6 reverts
// leg layer2 to MFMA via 64-row h2c staging (accs are MFMA-only chains ->
// AGPR-eligible; R2 allocated this shape at 96 VGPR, zero spill), keeps R3's
// transposed operands + packed b64 LDS writes, deletes legpart (stride-16
// conflict source), restrides ldiff 16->20. Prep packs 8 elems/thread with
// one dwordx4 store (was 8 scattered 2B stores).

#define E_ 4
#define B_ 16384
#define H1S 520   // bf16 elems; 1040B row: 16B-aligned, 4-bank skew (2-way = free)
#define H2S 136
#define A0S 40
#define LDS_ 20   // ldiff row stride (floats); 80B row: 16B-aligned, non-pow2

typedef float f32x4 __attribute__((ext_vector_type(4)));
typedef __bf16 bf16x8 __attribute__((ext_vector_type(8)));
typedef __bf16 bf16x4 __attribute__((ext_vector_type(4)));

__device__ __forceinline__ f32x4 mfma16(bf16x8 a, bf16x8 b, f32x4 c) {
  return __builtin_amdgcn_mfma_f32_16x16x32_bf16(a, b, c, 0, 0, 0);
}

__device__ __forceinline__ void fmt_map(int k, int& ib, int& j) {
  if (k < 8) { ib = k >> 1; j = (k & 1) ? 2 : 0; }
  else { int k8 = k - 8; ib = k8 >> 1; j = (k8 & 1) ? 3 : 1; }
}

// ---------------- prep: grouped pack, 8 elems -> one b128 store -------------
// Packed W (K x N), fragment group g = (nt*KT + kt)*64 + lane:
//   dst[g*8 + j] = W[kt*32 + ((lane>>4)&3)*8 + j][nt*16 + (lane&15)]
__device__ __forceinline__ void pack_g(int g, int KT, int Kreal, int Nsrc, int Nreal,
                                       const float* __restrict__ src,
                                       const float* __restrict__ sigma,
                                       __bf16* __restrict__ dst)
{
  int lane = g & 63, g2 = g >> 6;
  int nt = g2 / KT, kt = g2 - nt * KT;
  int n = nt * 16 + (lane & 15);
  int kb = kt * 32 + ((lane >> 4) & 3) * 8;
  bf16x8 tmp;
  #pragma unroll
  for (int j = 0; j < 8; ++j) {
    int k = kb + j;
    float v = 0.f;
    if (k < Kreal && n < Nreal) {
      v = src[(size_t)k * Nsrc + n];
      if (sigma) v *= 1.f / (sigma[k] + 1e-8f);
    }
    tmp[j] = (__bf16)v;
  }
  *(bf16x8*)(dst + (size_t)g * 8) = tmp;
}

__global__ void prep_kernel(const float* __restrict__ wl0, const float* __restrict__ wl1,
                            const float* __restrict__ wl2, const float* __restrict__ wp0,
                            const float* __restrict__ wp1, const float* __restrict__ wp2,
                            const float* __restrict__ bl0, const float* __restrict__ bp0,
                            const float* __restrict__ mu_leg, const float* __restrict__ sigma_leg,
                            const float* __restrict__ mu_pose, const float* __restrict__ sigma_pose,
                            __bf16* __restrict__ WL0p, __bf16* __restrict__ WL1p,
                            __bf16* __restrict__ WL2p, __bf16* __restrict__ WP0p,
                            __bf16* __restrict__ WP1p, __bf16* __restrict__ WP2p,
                            float* __restrict__ bl0f, float* __restrict__ bp0f)
{
  // group counts: WL0 8192 | WL1 131072 | WL2 4096 | WP0 8192 | WP1 131072 |
  //               WP2 4096 | bias threads 4096
  const int total = 8192 + 131072 + 4096 + 8192 + 131072 + 4096 + 4096;
  for (int idx0 = blockIdx.x * blockDim.x + threadIdx.x; idx0 < total;
       idx0 += gridDim.x * blockDim.x) {
    int x = idx0;
    if (x < 8192) {
      int e = x >> 11, g = x & 2047;
      pack_g(g, 1, 6, 512, 512, wl0 + (size_t)e * 6 * 512, sigma_leg, WL0p + e * 16384);
    } else if ((x -= 8192) < 131072) {
      int e = x >> 15, g = x & 32767;
      pack_g(g, 16, 512, 512, 512, wl1 + (size_t)e * 512 * 512, nullptr,
             WL1p + (size_t)e * 262144);
    } else if ((x -= 131072) < 4096) {
      int e = x >> 10, g = x & 1023;
      pack_g(g, 16, 512, 8, 8, wl2 + (size_t)e * 512 * 8, nullptr, WL2p + e * 8192);
    } else if ((x -= 4096) < 8192) {
      int e = x >> 11, g = x & 2047;
      pack_g(g, 1, 29, 512, 512, wp0 + (size_t)e * 29 * 512, sigma_pose, WP0p + e * 16384);
    } else if ((x -= 8192) < 131072) {
      int e = x >> 15, g = x & 32767;
      pack_g(g, 16, 512, 512, 512, wp1 + (size_t)e * 512 * 512, nullptr,
             WP1p + (size_t)e * 262144);
    } else if ((x -= 131072) < 4096) {
      int e = x >> 10, g = x & 1023;
      pack_g(g, 16, 512, 26, 16, wp2 + (size_t)e * 512 * 26, nullptr, WP2p + e * 8192);
    } else {
      x -= 4096;  // bias folds: b0' = b0 - sum_k mu[k]/(sigma[k]+eps) * W0[k,:]
      if (x < 2048) {
        int e = x >> 9, n = x & 511;
        float s = bl0[e * 512 + n];
        #pragma unroll
        for (int k = 0; k < 6; ++k)
          s -= mu_leg[k] / (sigma_leg[k] + 1e-8f) * wl0[(e * 6 + k) * 512 + n];
        bl0f[e * 512 + n] = s;
      } else {
        x -= 2048;
        int e = x >> 9, n = x & 511;
        float s = bp0[e * 512 + n];
        for (int k = 0; k < 29; ++k)
          s -= mu_pose[k] / (sigma_pose[k] + 1e-8f) * wp0[(e * 29 + k) * 512 + n];
        bp0f[e * 512 + n] = s;
      }
    }
  }
}

// ---------------- fused model kernel ----------------------------------------
__global__ __launch_bounds__(512, 1) void fused_kernel(
    const float* __restrict__ state, const float* __restrict__ act,
    const float* __restrict__ bl1, const float* __restrict__ bl2,
    const float* __restrict__ bp1, const float* __restrict__ bp2,
    const float* __restrict__ mu_t_leg, const float* __restrict__ sigma_t_leg,
    const float* __restrict__ mu_t_pose, const float* __restrict__ sigma_t_pose,
    const __bf16* __restrict__ WL0p, const __bf16* __restrict__ WL1p,
    const __bf16* __restrict__ WL2p, const __bf16* __restrict__ WP0p,
    const __bf16* __restrict__ WP1p, const __bf16* __restrict__ WP2p,
    const float* __restrict__ bl0f, const float* __restrict__ bp0f,
    float* __restrict__ out)
{
  __shared__ alignas(16) __bf16 h1[128 * H1S];   // 133120 B
  __shared__ alignas(16) __bf16 h2c[64 * H2S];   // 17408 B (union: a0 staging)
  __shared__ alignas(16) float ldiff[64][LDS_];  // 5120 B  -> total ~156 KB

  __bf16* a0s = h2c;                             // a0 <= 128*40*2 = 10240 B

  const int tid = threadIdx.x;
  const int wv = tid >> 6;
  const int lane = tid & 63;
  const int quad = lane >> 4;
  const int l16 = lane & 15;
  const int b0 = blockIdx.x * 64;

  f32x4 posacc = {0.f, 0.f, 0.f, 0.f};
  float legreg[2] = {0.f, 0.f};

  for (int e = 0; e < E_; ++e) {
    const float* se = state + (size_t)e * B_ * 29;
    const float* ae = act + (size_t)e * B_ * 8;

    // ================= leg MLP: 2 passes of 128 leg rows =================
    {
      const __bf16* W0 = WL0p + e * 16384;
      const __bf16* W1 = WL1p + (size_t)e * 262144;
      const __bf16* W2 = WL2p + e * 8192;
      const float* b0v = bl0f + e * 512;
      const float* b1v = bl1 + e * 512;

      for (int half = 0; half < 2; ++half) {
        __syncthreads();   // (A) a0s/h2c region free
        for (int i = tid; i < 128 * 32; i += 512) {
          int r = i >> 5, c = i & 31;
          float v = 0.f;
          if (c < 6) {
            int ib = r >> 5;
            int b = b0 + half * 32 + (r & 31);
            const float* sp = se + (size_t)b * 29;
            if (c == 0) v = sp[13 + 2 * ib];
            else if (c == 1) v = sp[21 + 2 * ib];
            else if (c == 2) v = sp[14 + 2 * ib];
            else if (c == 3) v = sp[22 + 2 * ib];
            else if (c == 4) v = ae[(size_t)b * 8 + 2 * ib];
            else v = ae[(size_t)b * 8 + 2 * ib + 1];
          }
          a0s[r * A0S + c] = (__bf16)v;
        }
        __syncthreads();   // (B) a0 ready

        // ---- layer0 (transposed): h1[row][n], packed b64 writes
        {
          bf16x8 wfr[4]; f32x4 bias[4];
          #pragma unroll
          for (int i = 0; i < 4; ++i) {
            int nt = wv * 4 + i;
            wfr[i] = *(const bf16x8*)(W0 + (nt * 64 + lane) * 8);
            bias[i] = *(const f32x4*)(b0v + nt * 16 + quad * 4);
          }
          for (int bt = 0; bt < 8; ++bt) {
            bf16x8 xfr = *(const bf16x8*)&a0s[(bt * 16 + l16) * A0S + quad * 8];
            #pragma unroll
            for (int i = 0; i < 4; ++i) {
              f32x4 acc = mfma16(wfr[i], xfr, bias[i]);
              bf16x4 p;
              #pragma unroll
              for (int r = 0; r < 4; ++r) p[r] = (__bf16)fmaxf(acc[r], 0.f);
              *(bf16x4*)&h1[(bt * 16 + l16) * H1S + (wv * 4 + i) * 16 + quad * 4] = p;
            }
          }
        }
        __syncthreads();   // (C) h1 ready

        // ---- layer1 + MFMA layer2 via 64-row h2c halves
        const int rg = wv >> 2;   // row half (64 rows)
        const int cg = wv & 3;    // n-group (2 n-tiles per cc)
        f32x4 oacc;               // layer2 acc: rows o=quad*4+r, col leg-row
        #pragma unroll
        for (int r = 0; r < 4; ++r) {
          int o = quad * 4 + r;
          oacc[r] = (o < 8) ? bl2[e * 8 + o] : 0.f;
        }

        for (int cc = 0; cc < 4; ++cc) {
          f32x4 acc[4][2];
          #pragma unroll
          for (int ct = 0; ct < 2; ++ct) {
            f32x4 bias = *(const f32x4*)(b1v + cc * 128 + (cg * 2 + ct) * 16 + quad * 4);
            #pragma unroll
            for (int bb = 0; bb < 4; ++bb) acc[bb][ct] = bias;
          }
          const int ntb = cc * 8 + cg * 2;
          #pragma unroll 2
          for (int kt = 0; kt < 16; ++kt) {
            bf16x8 wf0 = *(const bf16x8*)(W1 + ((size_t)((ntb + 0) * 16 + kt) * 64 + lane) * 8);
            bf16x8 wf1 = *(const bf16x8*)(W1 + ((size_t)((ntb + 1) * 16 + kt) * 64 + lane) * 8);
            bf16x8 hf[4];
            #pragma unroll
            for (int bb = 0; bb < 4; ++bb)
              hf[bb] = *(const bf16x8*)&h1[((rg * 4 + bb) * 16 + l16) * H1S + kt * 32 + quad * 8];
            #pragma unroll
            for (int bb = 0; bb < 4; ++bb) {
              acc[bb][0] = mfma16(wf0, hf[bb], acc[bb][0]);
              acc[bb][1] = mfma16(wf1, hf[bb], acc[bb][1]);
            }
          }
          // stage relu(h2) per 64-row half; owner waves run layer2 MFMA
          #pragma unroll
          for (int hh = 0; hh < 2; ++hh) {
            __syncthreads();
            if (rg == hh) {
              #pragma unroll
              for (int bb = 0; bb < 4; ++bb)
                #pragma unroll
                for (int ct = 0; ct < 2; ++ct) {
                  bf16x4 p;
                  #pragma unroll
                  for (int r = 0; r < 4; ++r) p[r] = (__bf16)fmaxf(acc[bb][ct][r], 0.f);
                  *(bf16x4*)&h2c[(bb * 16 + l16) * H2S + (cg * 2 + ct) * 16 + quad * 4] = p;
                }
            }
            __syncthreads();
            if (rg == hh) {   // wave handles batch-tile cg of this half
              #pragma unroll
              for (int k2 = 0; k2 < 4; ++k2) {
                bf16x8 hf2 = *(const bf16x8*)&h2c[(cg * 16 + l16) * H2S + k2 * 32 + quad * 8];
                bf16x8 wf2 = *(const bf16x8*)(W2 + ((cc * 4 + k2) * 64 + lane) * 8);
                oacc = mfma16(wf2, hf2, oacc);
              }
            }
          }
        }
        // ---- leg epilogue: lane (quad==0) holds o=0..3 for leg-row L
        if (quad == 0) {
          f32x4 sc = *(const f32x4*)sigma_t_leg;
          f32x4 mv = *(const f32x4*)mu_t_leg;
          int L = rg * 64 + cg * 16 + l16;   // = ib*32 + t
          f32x4 v;
          #pragma unroll
          for (int r = 0; r < 4; ++r) v[r] = oacc[r] * (sc[r] + 1e-8f) + mv[r];
          *(f32x4*)&ldiff[half * 32 + (L & 31)][(L >> 5) * 4] = v;
        }
      } // half
    }
    __syncthreads();       // (E) ldiff ready, h2c free

    // ================= pose MLP: 64 rows =================
    for (int i = tid; i < 64 * 32; i += 512) {
      int t = i >> 5, c = i & 31;
      float v = 0.f;
      if (c < 13) v = se[(size_t)(b0 + t) * 29 + c];
      else if (c < 29) { int ib, j; fmt_map(c - 13, ib, j); v = ldiff[t][ib * 4 + j]; }
      a0s[t * A0S + c] = (__bf16)v;
    }
    {  // legs output accumulation (registers)
      #pragma unroll
      for (int jj = 0; jj < 2; ++jj) {
        int idx = tid * 2 + jj, t = idx >> 4, k = idx & 15;
        int ib, j; fmt_map(k, ib, j);
        legreg[jj] += se[(size_t)(b0 + t) * 29 + 13 + k] + ldiff[t][ib * 4 + j];
      }
    }
    __syncthreads();       // (F) a0p ready

    // ---- pose layer0
    {
      const __bf16* W0 = WP0p + e * 16384;
      const float* b0v = bp0f + e * 512;
      bf16x8 wfr[4]; f32x4 bias[4];
      #pragma unroll
      for (int i = 0; i < 4; ++i) {
        int nt = wv * 4 + i;
        wfr[i] = *(const bf16x8*)(W0 + (nt * 64 + lane) * 8);
        bias[i] = *(const f32x4*)(b0v + nt * 16 + quad * 4);
      }
      for (int bt = 0; bt < 4; ++bt) {
        bf16x8 xfr = *(const bf16x8*)&a0s[(bt * 16 + l16) * A0S + quad * 8];
        #pragma unroll
        for (int i = 0; i < 4; ++i) {
          f32x4 acc = mfma16(wfr[i], xfr, bias[i]);
          bf16x4 p;
          #pragma unroll
          for (int r = 0; r < 4; ++r) p[r] = (__bf16)fmaxf(acc[r], 0.f);
          *(bf16x4*)&h1[(bt * 16 + l16) * H1S + (wv * 4 + i) * 16 + quad * 4] = p;
        }
      }
    }
    __syncthreads();       // (G) h1 ready (a0p reads done)

    // ---- pose layer1 + MFMA layer2 via h2c
    {
      const __bf16* W1 = WP1p + (size_t)e * 262144;
      const __bf16* W2 = WP2p + e * 8192;
      const float* b1v = bp1 + e * 512;
      const int ng = wv >> 1;   // 2 n-tiles
      const int bg = wv & 1;    // 2 batch-tiles
      f32x4 po;
      #pragma unroll
      for (int r = 0; r < 4; ++r) po[r] = bp2[e * 26 + quad * 4 + r];

      for (int cc = 0; cc < 4; ++cc) {
        f32x4 acc[2][2];
        #pragma unroll
        for (int ct = 0; ct < 2; ++ct) {
          f32x4 bias = *(const f32x4*)(b1v + cc * 128 + (ng * 2 + ct) * 16 + quad * 4);
          #pragma unroll
          for (int bb = 0; bb < 2; ++bb) acc[bb][ct] = bias;
        }
        const int ntb = cc * 8 + ng * 2;
        #pragma unroll 2
        for (int kt = 0; kt < 16; ++kt) {
          bf16x8 wf0 = *(const bf16x8*)(W1 + ((size_t)((ntb + 0) * 16 + kt) * 64 + lane) * 8);
          bf16x8 wf1 = *(const bf16x8*)(W1 + ((size_t)((ntb + 1) * 16 + kt) * 64 + lane) * 8);
          bf16x8 hf[2];
          #pragma unroll
          for (int bb = 0; bb < 2; ++bb)
            hf[bb] = *(const bf16x8*)&h1[((bg * 2 + bb) * 16 + l16) * H1S + kt * 32 + quad * 8];
          #pragma unroll
          for (int bb = 0; bb < 2; ++bb) {
            acc[bb][0] = mfma16(wf0, hf[bb], acc[bb][0]);
            acc[bb][1] = mfma16(wf1, hf[bb], acc[bb][1]);
          }
        }
        __syncthreads();   // (H) h2c free
        #pragma unroll
        for (int bb = 0; bb < 2; ++bb) {
          #pragma unroll
          for (int ct = 0; ct < 2; ++ct) {
            bf16x4 p;
            #pragma unroll
            for (int r = 0; r < 4; ++r) p[r] = (__bf16)fmaxf(acc[bb][ct][r], 0.f);
            *(bf16x4*)&h2c[((bg * 2 + bb) * 16 + l16) * H2S + (ng * 2 + ct) * 16 + quad * 4] = p;
          }
        }
        __syncthreads();   // (I) h2 ready
        if (wv < 4) {
          #pragma unroll
          for (int k2 = 0; k2 < 4; ++k2) {
            bf16x8 hf2 = *(const bf16x8*)&h2c[(wv * 16 + l16) * H2S + k2 * 32 + quad * 8];
            bf16x8 wf2 = *(const bf16x8*)(W2 + ((cc * 4 + k2) * 64 + lane) * 8);
            po = mfma16(wf2, hf2, po);
          }
        }
      }
      // pose epilogue: accumulate in registers across ensembles
      if (wv < 4) {
        #pragma unroll
        for (int r = 0; r < 4; ++r) {
          int o = quad * 4 + r;
          if (o < 13)
            posacc[r] += po[r] * (sigma_t_pose[o] + 1e-8f) + mu_t_pose[o] +
                         se[(size_t)(b0 + wv * 16 + l16) * 29 + o];
        }
      }
    }
  } // e

  // ================= final writes: mean over ensembles =================
  if (wv < 4) {
    #pragma unroll
    for (int r = 0; r < 4; ++r) {
      int o = quad * 4 + r;
      if (o < 13)
        out[(size_t)(b0 + wv * 16 + l16) * 29 + o] = 0.25f * posacc[r];
    }
  }
  #pragma unroll
  for (int jj = 0; jj < 2; ++jj) {
    int idx = tid * 2 + jj, t = idx >> 4, k = idx & 15;
    out[(size_t)(b0 + t) * 29 + 13 + k] = 0.25f * legreg[jj];
  }
}

// ---------------- launch ----------------------------------------------------
extern "C" void kernel_launch(void* const* d_in, const int* in_sizes, int n_in,
                              void* d_out, int out_size, void* d_ws, size_t ws_size,
                              hipStream_t stream) {
  const float* state = (const float*)d_in[0];
  const float* act = (const float*)d_in[1];
  const float* wl0 = (const float*)d_in[2];
  const float* bl0 = (const float*)d_in[3];
  const float* wl1 = (const float*)d_in[4];
  const float* bl1 = (const float*)d_in[5];
  const float* wl2 = (const float*)d_in[6];
  const float* bl2 = (const float*)d_in[7];
  const float* wp0 = (const float*)d_in[8];
  const float* bp0 = (const float*)d_in[9];
  const float* wp1 = (const float*)d_in[10];
  const float* bp1 = (const float*)d_in[11];
  const float* wp2 = (const float*)d_in[12];
  const float* bp2 = (const float*)d_in[13];
  const float* mu_leg = (const float*)d_in[14];
  const float* sigma_leg = (const float*)d_in[15];
  const float* mu_pose = (const float*)d_in[16];
  const float* sigma_pose = (const float*)d_in[17];
  const float* mu_t_leg = (const float*)d_in[18];
  const float* sigma_t_leg = (const float*)d_in[19];
  const float* mu_t_pose = (const float*)d_in[20];
  const float* sigma_t_pose = (const float*)d_in[21];
  float* out = (float*)d_out;

  char* ws = (char*)d_ws;
  __bf16* WL0p = (__bf16*)(ws);                  // 131072
  __bf16* WL1p = (__bf16*)(ws + 131072);         // 2097152
  __bf16* WL2p = (__bf16*)(ws + 2228224);        // 65536
  __bf16* WP0p = (__bf16*)(ws + 2293760);        // 131072
  __bf16* WP1p = (__bf16*)(ws + 2424832);        // 2097152
  __bf16* WP2p = (__bf16*)(ws + 4521984);        // 65536
  float* bl0f = (float*)(ws + 4587520);          // 8192
  float* bp0f = (float*)(ws + 4595712);          // 8192

  prep_kernel<<<512, 256, 0, stream>>>(wl0, wl1, wl2, wp0, wp1, wp2, bl0, bp0,
                                       mu_leg, sigma_leg, mu_pose, sigma_pose,
                                       WL0p, WL1p, WL2p, WP0p, WP1p, WP2p,
                                       bl0f, bp0f);
  fused_kernel<<<256, 512, 0, stream>>>(state, act, bl1, bl2, bp1, bp2,
                                        mu_t_leg, sigma_t_leg, mu_t_pose, sigma_t_pose,
                                        WL0p, WL1p, WL2p, WP0p, WP1p, WP2p,
                                        bl0f, bp0f, out);
}

// Round 7
// 402.631 us; speedup vs baseline: 1.6923x; 1.1753x over previous
//
#include <hip/hip_runtime.h>

// NPG model: E=4, B=16384, STATE=29, ACT=8, HID=512.
// R7: operand-bandwidth fix. R6 was LDS+L2 bound at wave tile 64rx32c
// (6KB operands per 8 MFMA -> ~20% MfmaUtil ceiling, measured 20%).
// R7 wave tile = 128r x 64c (acc[8][4] = 128 AGPRs, OK at 2 waves/SIMD):
// per kt 8 LDS + 4 L2 b128 -> 32 MFMA (2x MACs/byte), no cc loop,
// h1 re-read 16x->8x, W1 L2 traffic halved. Leg layer2 = VALU on acc AFTER
// the kt loop (live ranges don't overlap -> no R3-style spill), partials via
// LDS. Pose layer2 stages h2 into h1's unused upper 64 rows (2 syncs).
// ~48 barriers/block (was ~200). unroll 1 on kt loops caps reg pressure.

#define E_ 4
#define B_ 16384
#define H1S 520   // bf16 elems; 1040B row: 16B-aligned, 4-bank skew
#define A0S 40
#define LDS_ 20   // ldiff row stride (floats)

typedef float f32x4 __attribute__((ext_vector_type(4)));
typedef __bf16 bf16x8 __attribute__((ext_vector_type(8)));
typedef __bf16 bf16x4 __attribute__((ext_vector_type(4)));

__device__ __forceinline__ f32x4 mfma16(bf16x8 a, bf16x8 b, f32x4 c) {
  return __builtin_amdgcn_mfma_f32_16x16x32_bf16(a, b, c, 0, 0, 0);
}

__device__ __forceinline__ void fmt_map(int k, int& ib, int& j) {
  if (k < 8) { ib = k >> 1; j = (k & 1) ? 2 : 0; }
  else { int k8 = k - 8; ib = k8 >> 1; j = (k8 & 1) ? 3 : 1; }
}

// ---------------- prep: grouped pack, 8 elems -> one b128 store -------------
__device__ __forceinline__ void pack_g(int g, int KT, int Kreal, int Nsrc, int Nreal,
                                       const float* __restrict__ src,
                                       const float* __restrict__ sigma,
                                       __bf16* __restrict__ dst)
{
  int lane = g & 63, g2 = g >> 6;
  int nt = g2 / KT, kt = g2 - nt * KT;
  int n = nt * 16 + (lane & 15);
  int kb = kt * 32 + ((lane >> 4) & 3) * 8;
  bf16x8 tmp;
  #pragma unroll
  for (int j = 0; j < 8; ++j) {
    int k = kb + j;
    float v = 0.f;
    if (k < Kreal && n < Nreal) {
      v = src[(size_t)k * Nsrc + n];
      if (sigma) v *= 1.f / (sigma[k] + 1e-8f);
    }
    tmp[j] = (__bf16)v;
  }
  *(bf16x8*)(dst + (size_t)g * 8) = tmp;
}

__global__ void prep_kernel(const float* __restrict__ wl0, const float* __restrict__ wl1,
                            const float* __restrict__ wp0,
                            const float* __restrict__ wp1, const float* __restrict__ wp2,
                            const float* __restrict__ bl0, const float* __restrict__ bp0,
                            const float* __restrict__ mu_leg, const float* __restrict__ sigma_leg,
                            const float* __restrict__ mu_pose, const float* __restrict__ sigma_pose,
                            __bf16* __restrict__ WL0p, __bf16* __restrict__ WL1p,
                            __bf16* __restrict__ WP0p, __bf16* __restrict__ WP1p,
                            __bf16* __restrict__ WP2p,
                            float* __restrict__ bl0f, float* __restrict__ bp0f)
{
  // groups: WL0 8192 | WL1 131072 | WP0 8192 | WP1 131072 | WP2 4096 | bias 4096
  const int total = 8192 + 131072 + 8192 + 131072 + 4096 + 4096;
  for (int idx0 = blockIdx.x * blockDim.x + threadIdx.x; idx0 < total;
       idx0 += gridDim.x * blockDim.x) {
    int x = idx0;
    if (x < 8192) {
      int e = x >> 11, g = x & 2047;
      pack_g(g, 1, 6, 512, 512, wl0 + (size_t)e * 6 * 512, sigma_leg, WL0p + e * 16384);
    } else if ((x -= 8192) < 131072) {
      int e = x >> 15, g = x & 32767;
      pack_g(g, 16, 512, 512, 512, wl1 + (size_t)e * 512 * 512, nullptr,
             WL1p + (size_t)e * 262144);
    } else if ((x -= 131072) < 8192) {
      int e = x >> 11, g = x & 2047;
      pack_g(g, 1, 29, 512, 512, wp0 + (size_t)e * 29 * 512, sigma_pose, WP0p + e * 16384);
    } else if ((x -= 8192) < 131072) {
      int e = x >> 15, g = x & 32767;
      pack_g(g, 16, 512, 512, 512, wp1 + (size_t)e * 512 * 512, nullptr,
             WP1p + (size_t)e * 262144);
    } else if ((x -= 131072) < 4096) {
      int e = x >> 10, g = x & 1023;
      pack_g(g, 16, 512, 26, 16, wp2 + (size_t)e * 512 * 26, nullptr, WP2p + e * 8192);
    } else {
      x -= 4096;  // bias folds: b0' = b0 - sum_k mu[k]/(sigma[k]+eps) * W0[k,:]
      if (x < 2048) {
        int e = x >> 9, n = x & 511;
        float s = bl0[e * 512 + n];
        #pragma unroll
        for (int k = 0; k < 6; ++k)
          s -= mu_leg[k] / (sigma_leg[k] + 1e-8f) * wl0[(e * 6 + k) * 512 + n];
        bl0f[e * 512 + n] = s;
      } else {
        x -= 2048;
        int e = x >> 9, n = x & 511;
        float s = bp0[e * 512 + n];
        for (int k = 0; k < 29; ++k)
          s -= mu_pose[k] / (sigma_pose[k] + 1e-8f) * wp0[(e * 29 + k) * 512 + n];
        bp0f[e * 512 + n] = s;
      }
    }
  }
}

// ---------------- fused model kernel ----------------------------------------
__global__ __launch_bounds__(512, 1) void fused_kernel(
    const float* __restrict__ state, const float* __restrict__ act,
    const float* __restrict__ bl1, const float* __restrict__ bl2,
    const float* __restrict__ bp1, const float* __restrict__ bp2,
    const float* __restrict__ wl2,  // fp32, VALU leg layer2
    const float* __restrict__ mu_t_leg, const float* __restrict__ sigma_t_leg,
    const float* __restrict__ mu_t_pose, const float* __restrict__ sigma_t_pose,
    const __bf16* __restrict__ WL0p, const __bf16* __restrict__ WL1p,
    const __bf16* __restrict__ WP0p, const __bf16* __restrict__ WP1p,
    const __bf16* __restrict__ WP2p,
    const float* __restrict__ bl0f, const float* __restrict__ bp0f,
    float* __restrict__ out)
{
  __shared__ alignas(16) __bf16 h1[128 * H1S];    // 133120 B (pose: h2 in rows 64..127)
  __shared__ alignas(16) char Ubuf[17408];        // union: a0 staging / legpart
  __shared__ alignas(16) float ldiff[64][LDS_];   // 5120 B -> total 155648 B
  __bf16* a0s = (__bf16*)Ubuf;
  float* legpart = (float*)Ubuf;                  // [wv][128][4] = 16384 B

  const int tid = threadIdx.x;
  const int wv = tid >> 6;
  const int lane = tid & 63;
  const int quad = lane >> 4;
  const int l16 = lane & 15;
  const int b0 = blockIdx.x * 64;

  f32x4 posacc = {0.f, 0.f, 0.f, 0.f};
  float legreg[2] = {0.f, 0.f};

  for (int e = 0; e < E_; ++e) {
    const float* se = state + (size_t)e * B_ * 29;
    const float* ae = act + (size_t)e * B_ * 8;

    // ================= leg MLP: 2 passes of 128 leg rows =================
    {
      const __bf16* W0 = WL0p + e * 16384;
      const __bf16* W1 = WL1p + (size_t)e * 262144;
      const float* b0v = bl0f + e * 512;
      const float* b1v = bl1 + e * 512;
      const float* w2l = wl2 + (size_t)e * 4096;  // 512x8 fp32

      for (int half = 0; half < 2; ++half) {
        __syncthreads();   // (A) Ubuf free
        for (int i = tid; i < 128 * 32; i += 512) {
          int r = i >> 5, c = i & 31;
          float v = 0.f;
          if (c < 6) {
            int ib = r >> 5;
            int b = b0 + half * 32 + (r & 31);
            const float* sp = se + (size_t)b * 29;
            if (c == 0) v = sp[13 + 2 * ib];
            else if (c == 1) v = sp[21 + 2 * ib];
            else if (c == 2) v = sp[14 + 2 * ib];
            else if (c == 3) v = sp[22 + 2 * ib];
            else if (c == 4) v = ae[(size_t)b * 8 + 2 * ib];
            else v = ae[(size_t)b * 8 + 2 * ib + 1];
          }
          a0s[r * A0S + c] = (__bf16)v;
        }
        __syncthreads();   // (B) a0 ready

        // ---- layer0: h1[row][n], packed b64 writes
        {
          bf16x8 wfr[4]; f32x4 bias[4];
          #pragma unroll
          for (int i = 0; i < 4; ++i) {
            int nt = wv * 4 + i;
            wfr[i] = *(const bf16x8*)(W0 + (nt * 64 + lane) * 8);
            bias[i] = *(const f32x4*)(b0v + nt * 16 + quad * 4);
          }
          for (int bt = 0; bt < 8; ++bt) {
            bf16x8 xfr = *(const bf16x8*)&a0s[(bt * 16 + l16) * A0S + quad * 8];
            #pragma unroll
            for (int i = 0; i < 4; ++i) {
              f32x4 acc = mfma16(wfr[i], xfr, bias[i]);
              bf16x4 p;
              #pragma unroll
              for (int r = 0; r < 4; ++r) p[r] = (__bf16)fmaxf(acc[r], 0.f);
              *(bf16x4*)&h1[(bt * 16 + l16) * H1S + (wv * 4 + i) * 16 + quad * 4] = p;
            }
          }
        }
        __syncthreads();   // (C) h1 ready

        // ---- layer1: wave tile 128r x 64c, acc[8][4] (AGPR)
        f32x4 acc[8][4];
        #pragma unroll
        for (int i = 0; i < 4; ++i) {
          f32x4 bias = *(const f32x4*)(b1v + (wv * 4 + i) * 16 + quad * 4);
          #pragma unroll
          for (int bb = 0; bb < 8; ++bb) acc[bb][i] = bias;
        }
        #pragma unroll 1
        for (int kt = 0; kt < 16; ++kt) {
          bf16x8 wf[4];
          #pragma unroll
          for (int i = 0; i < 4; ++i)
            wf[i] = *(const bf16x8*)(W1 + ((size_t)((wv * 4 + i) * 16 + kt) * 64 + lane) * 8);
          bf16x8 hf[8];
          #pragma unroll
          for (int bb = 0; bb < 8; ++bb)
            hf[bb] = *(const bf16x8*)&h1[(bb * 16 + l16) * H1S + kt * 32 + quad * 8];
          #pragma unroll
          for (int bb = 0; bb < 8; ++bb)
            #pragma unroll
            for (int i = 0; i < 4; ++i)
              acc[bb][i] = mfma16(wf[i], hf[bb], acc[bb][i]);
        }

        // ---- layer2 (VALU, o=0..3), after MFMA live range closes
        f32x4 po[8];
        #pragma unroll
        for (int bb = 0; bb < 8; ++bb) po[bb] = (f32x4){0.f, 0.f, 0.f, 0.f};
        #pragma unroll
        for (int i = 0; i < 4; ++i) {
          #pragma unroll
          for (int r = 0; r < 4; ++r) {
            int n = (wv * 4 + i) * 16 + quad * 4 + r;
            f32x4 w2v = *(const f32x4*)(w2l + n * 8);
            #pragma unroll
            for (int bb = 0; bb < 8; ++bb)
              po[bb] += fmaxf(acc[bb][i][r], 0.f) * w2v;
          }
        }
        #pragma unroll
        for (int bb = 0; bb < 8; ++bb) {
          #pragma unroll
          for (int c = 0; c < 4; ++c) {
            po[bb][c] += __shfl_xor(po[bb][c], 16);
            po[bb][c] += __shfl_xor(po[bb][c], 32);
          }
        }
        if (quad == 0) {
          #pragma unroll
          for (int bb = 0; bb < 8; ++bb)
            *(f32x4*)&legpart[wv * 512 + (bb * 16 + l16) * 4] = po[bb];
        }
        __syncthreads();   // (D) legpart ready
        {
          int L = tid >> 2, o = tid & 3;
          float s = bl2[e * 8 + o];
          #pragma unroll
          for (int w = 0; w < 8; ++w) s += legpart[w * 512 + L * 4 + o];
          s = s * (sigma_t_leg[o] + 1e-8f) + mu_t_leg[o];
          ldiff[half * 32 + (L & 31)][(L >> 5) * 4 + o] = s;
        }
      } // half
    }
    __syncthreads();       // (E) ldiff ready, Ubuf free

    // ================= pose MLP: 64 rows =================
    for (int i = tid; i < 64 * 32; i += 512) {
      int t = i >> 5, c = i & 31;
      float v = 0.f;
      if (c < 13) v = se[(size_t)(b0 + t) * 29 + c];
      else if (c < 29) { int ib, j; fmt_map(c - 13, ib, j); v = ldiff[t][ib * 4 + j]; }
      a0s[t * A0S + c] = (__bf16)v;
    }
    {  // legs output accumulation (registers)
      #pragma unroll
      for (int jj = 0; jj < 2; ++jj) {
        int idx = tid * 2 + jj, t = idx >> 4, k = idx & 15;
        int ib, j; fmt_map(k, ib, j);
        legreg[jj] += se[(size_t)(b0 + t) * 29 + 13 + k] + ldiff[t][ib * 4 + j];
      }
    }
    __syncthreads();       // (F) a0p ready

    // ---- pose layer0 (h1 rows 0..63)
    {
      const __bf16* W0 = WP0p + e * 16384;
      const float* b0v = bp0f + e * 512;
      bf16x8 wfr[4]; f32x4 bias[4];
      #pragma unroll
      for (int i = 0; i < 4; ++i) {
        int nt = wv * 4 + i;
        wfr[i] = *(const bf16x8*)(W0 + (nt * 64 + lane) * 8);
        bias[i] = *(const f32x4*)(b0v + nt * 16 + quad * 4);
      }
      for (int bt = 0; bt < 4; ++bt) {
        bf16x8 xfr = *(const bf16x8*)&a0s[(bt * 16 + l16) * A0S + quad * 8];
        #pragma unroll
        for (int i = 0; i < 4; ++i) {
          f32x4 acc = mfma16(wfr[i], xfr, bias[i]);
          bf16x4 p;
          #pragma unroll
          for (int r = 0; r < 4; ++r) p[r] = (__bf16)fmaxf(acc[r], 0.f);
          *(bf16x4*)&h1[(bt * 16 + l16) * H1S + (wv * 4 + i) * 16 + quad * 4] = p;
        }
      }
    }
    __syncthreads();       // (G) h1 ready (a0p reads done)

    // ---- pose layer1: wave tile 64r x 64c; h2 -> h1 rows 64..127
    {
      const __bf16* W1 = WP1p + (size_t)e * 262144;
      const __bf16* W2 = WP2p + e * 8192;
      const float* b1v = bp1 + e * 512;

      f32x4 acc[4][4];
      #pragma unroll
      for (int i = 0; i < 4; ++i) {
        f32x4 bias = *(const f32x4*)(b1v + (wv * 4 + i) * 16 + quad * 4);
        #pragma unroll
        for (int bb = 0; bb < 4; ++bb) acc[bb][i] = bias;
      }
      #pragma unroll 1
      for (int kt = 0; kt < 16; ++kt) {
        bf16x8 wf[4];
        #pragma unroll
        for (int i = 0; i < 4; ++i)
          wf[i] = *(const bf16x8*)(W1 + ((size_t)((wv * 4 + i) * 16 + kt) * 64 + lane) * 8);
        bf16x8 hf[4];
        #pragma unroll
        for (int bb = 0; bb < 4; ++bb)
          hf[bb] = *(const bf16x8*)&h1[(bb * 16 + l16) * H1S + kt * 32 + quad * 8];
        #pragma unroll
        for (int bb = 0; bb < 4; ++bb)
          #pragma unroll
          for (int i = 0; i < 4; ++i)
            acc[bb][i] = mfma16(wf[i], hf[bb], acc[bb][i]);
      }
      // write relu(h2) to h1 upper rows (disjoint from layer1 reads; no sync)
      #pragma unroll
      for (int bb = 0; bb < 4; ++bb) {
        #pragma unroll
        for (int i = 0; i < 4; ++i) {
          bf16x4 p;
          #pragma unroll
          for (int r = 0; r < 4; ++r) p[r] = (__bf16)fmaxf(acc[bb][i][r], 0.f);
          *(bf16x4*)&h1[(64 + bb * 16 + l16) * H1S + (wv * 4 + i) * 16 + quad * 4] = p;
        }
      }
      __syncthreads();     // (H) h2 ready

      // ---- pose layer2: waves 0..3, full K=512
      if (wv < 4) {
        f32x4 po2;
        #pragma unroll
        for (int r = 0; r < 4; ++r) po2[r] = bp2[e * 26 + quad * 4 + r];
        #pragma unroll 1
        for (int k2 = 0; k2 < 16; ++k2) {
          bf16x8 hf2 = *(const bf16x8*)&h1[(64 + wv * 16 + l16) * H1S + k2 * 32 + quad * 8];
          bf16x8 wf2 = *(const bf16x8*)(W2 + ((size_t)k2 * 64 + lane) * 8);
          po2 = mfma16(wf2, hf2, po2);
        }
        #pragma unroll
        for (int r = 0; r < 4; ++r) {
          int o = quad * 4 + r;
          if (o < 13)
            posacc[r] += po2[r] * (sigma_t_pose[o] + 1e-8f) + mu_t_pose[o] +
                         se[(size_t)(b0 + wv * 16 + l16) * 29 + o];
        }
      }
    }
  } // e

  // ================= final writes: mean over ensembles =================
  if (wv < 4) {
    #pragma unroll
    for (int r = 0; r < 4; ++r) {
      int o = quad * 4 + r;
      if (o < 13)
        out[(size_t)(b0 + wv * 16 + l16) * 29 + o] = 0.25f * posacc[r];
    }
  }
  #pragma unroll
  for (int jj = 0; jj < 2; ++jj) {
    int idx = tid * 2 + jj, t = idx >> 4, k = idx & 15;
    out[(size_t)(b0 + t) * 29 + 13 + k] = 0.25f * legreg[jj];
  }
}

// ---------------- launch ----------------------------------------------------
extern "C" void kernel_launch(void* const* d_in, const int* in_sizes, int n_in,
                              void* d_out, int out_size, void* d_ws, size_t ws_size,
                              hipStream_t stream) {
  const float* state = (const float*)d_in[0];
  const float* act = (const float*)d_in[1];
  const float* wl0 = (const float*)d_in[2];
  const float* bl0 = (const float*)d_in[3];
  const float* wl1 = (const float*)d_in[4];
  const float* bl1 = (const float*)d_in[5];
  const float* wl2 = (const float*)d_in[6];
  const float* bl2 = (const float*)d_in[7];
  const float* wp0 = (const float*)d_in[8];
  const float* bp0 = (const float*)d_in[9];
  const float* wp1 = (const float*)d_in[10];
  const float* bp1 = (const float*)d_in[11];
  const float* wp2 = (const float*)d_in[12];
  const float* bp2 = (const float*)d_in[13];
  const float* mu_leg = (const float*)d_in[14];
  const float* sigma_leg = (const float*)d_in[15];
  const float* mu_pose = (const float*)d_in[16];
  const float* sigma_pose = (const float*)d_in[17];
  const float* mu_t_leg = (const float*)d_in[18];
  const float* sigma_t_leg = (const float*)d_in[19];
  const float* mu_t_pose = (const float*)d_in[20];
  const float* sigma_t_pose = (const float*)d_in[21];
  float* out = (float*)d_out;

  char* ws = (char*)d_ws;
  __bf16* WL0p = (__bf16*)(ws);                  // 131072
  __bf16* WL1p = (__bf16*)(ws + 131072);         // 2097152
  __bf16* WP0p = (__bf16*)(ws + 2228224);        // 131072
  __bf16* WP1p = (__bf16*)(ws + 2359296);        // 2097152
  __bf16* WP2p = (__bf16*)(ws + 4456448);        // 65536
  float* bl0f = (float*)(ws + 4521984);          // 8192
  float* bp0f = (float*)(ws + 4530176);          // 8192

  prep_kernel<<<512, 256, 0, stream>>>(wl0, wl1, wp0, wp1, wp2, bl0, bp0,
                                       mu_leg, sigma_leg, mu_pose, sigma_pose,
                                       WL0p, WL1p, WP0p, WP1p, WP2p, bl0f, bp0f);
  fused_kernel<<<256, 512, 0, stream>>>(state, act, bl1, bl2, bp1, bp2, wl2,
                                        mu_t_leg, sigma_t_leg, mu_t_pose, sigma_t_pose,
                                        WL0p, WL1p, WP0p, WP1p, WP2p,
                                        bl0f, bp0f, out);
}